// Round 12
// baseline (534.287 us; speedup 1.0000x reference)
//
#include <hip/hip_runtime.h>
#include <hip/hip_bf16.h>

#define B_ 4
#define N_ 10000
#define E_ 80000
#define D_ 256
#define BN_ (B_*N_)
#define MPAD 40064
#define SCAN_NBLK ((BN_ + 255) / 256)

typedef __attribute__((ext_vector_type(8))) short short8;
typedef __attribute__((ext_vector_type(4))) float f32x4;
typedef __attribute__((ext_vector_type(4))) unsigned short u16x4;

static __device__ __forceinline__ float wave_sum(float v){
  #pragma unroll
  for(int o=32;o>0;o>>=1) v += __shfl_xor(v, o);
  return v;
}

static __device__ __forceinline__ float block_sum(float v, float* red){
  v = wave_sum(v);
  int w = threadIdx.x >> 6;
  if((threadIdx.x & 63) == 0) red[w] = v;
  __syncthreads();
  float r = (red[0] + red[1]) + (red[2] + red[3]);
  __syncthreads();
  return r;
}

static __device__ __forceinline__ unsigned short f2bf(float f){
  unsigned u = __float_as_uint(f);
  return (unsigned short)((u + 0x7fffu + ((u>>16)&1u)) >> 16);
}
static __device__ __forceinline__ float bf2f(unsigned short b){
  return __uint_as_float(((unsigned)b) << 16);
}

// ------- node input projection + LN0 + relu -> hn0 (bf16) -------
__global__ __launch_bounds__(256) void k_node_in(
    const float* __restrict__ nf, const float* __restrict__ gf,
    const float* __restrict__ W, const float* __restrict__ bias,
    const float* __restrict__ lns, const float* __restrict__ lnb,
    unsigned short* __restrict__ hnbf){
  __shared__ float in_s[16][96];
  __shared__ float h_s[16][256];
  int base = blockIdx.x * 16;
  int tid = threadIdx.x;
  for(int idx = tid; idx < 16*96; idx += 256){
    int i = idx / 96, k = idx - i*96;
    int row = base + i;
    int b = row / N_;
    float v = (k < 64) ? nf[(size_t)row*64 + k] : gf[b*32 + (k-64)];
    in_s[i][k] = v;
  }
  __syncthreads();
  int c = tid;
  float acc[16];
  #pragma unroll
  for(int i=0;i<16;i++) acc[i]=0.f;
  for(int k=0;k<96;k+=4){
    float w0 = W[(k+0)*D_+c], w1 = W[(k+1)*D_+c];
    float w2 = W[(k+2)*D_+c], w3 = W[(k+3)*D_+c];
    #pragma unroll
    for(int i=0;i<16;i++){
      float4 a = *reinterpret_cast<const float4*>(&in_s[i][k]);
      acc[i] += a.x*w0 + a.y*w1 + a.z*w2 + a.w*w3;
    }
  }
  float bc = bias[c];
  #pragma unroll
  for(int i=0;i<16;i++) h_s[i][c] = acc[i] + bc;
  __syncthreads();
  int wv = tid>>6, lane = tid&63;
  float4 s4 = *reinterpret_cast<const float4*>(&lns[lane*4]);
  float4 b4 = *reinterpret_cast<const float4*>(&lnb[lane*4]);
  #pragma unroll
  for(int rr=0; rr<4; ++rr){
    int i = wv*4 + rr;
    float4 x = *reinterpret_cast<const float4*>(&h_s[i][lane*4]);
    float sum = x.x+x.y+x.z+x.w;
    float sq = x.x*x.x+x.y*x.y+x.z*x.z+x.w*x.w;
    #pragma unroll
    for(int o=32;o>0;o>>=1){ sum += __shfl_xor(sum,o); sq += __shfl_xor(sq,o); }
    float mean = sum*(1.f/256.f);
    float var = sq*(1.f/256.f) - mean*mean;
    float rs = rsqrtf(var + 1e-6f);
    u16x4 o;
    o.x = f2bf(fmaxf((x.x-mean)*rs*s4.x + b4.x, 0.f));
    o.y = f2bf(fmaxf((x.y-mean)*rs*s4.y + b4.y, 0.f));
    o.z = f2bf(fmaxf((x.z-mean)*rs*s4.z + b4.z, 0.f));
    o.w = f2bf(fmaxf((x.w-mean)*rs*s4.w + b4.w, 0.f));
    *reinterpret_cast<u16x4*>(&hnbf[(size_t)(base+i)*D_ + lane*4]) = o;
  }
}

// ---------------- CSR build ----------------
__global__ __launch_bounds__(256) void k_hist(
    const int* __restrict__ el, const int* __restrict__ emask,
    int* __restrict__ counts){
  int e = blockIdx.x*256 + threadIdx.x;
  if(e >= B_*E_) return;
  if(emask[e]){
    int b = e / E_;
    int r = el[(size_t)e*2 + 1];
    atomicAdd(&counts[b*N_ + r], 1);
  }
}

// ---- 3-phase multi-block exclusive scan of counts[BN_] -> offsets[BN_+1] ----
__global__ __launch_bounds__(256) void k_scanA(
    const int* __restrict__ counts, int* __restrict__ bsum){
  __shared__ int red[4];
  int idx = blockIdx.x*256 + threadIdx.x;
  int x = (idx < BN_) ? counts[idx] : 0;
  int lane = threadIdx.x & 63, w = threadIdx.x >> 6;
  int s = x;
  #pragma unroll
  for(int o=32;o>0;o>>=1) s += __shfl_xor(s, o);
  if(lane == 0) red[w] = s;
  __syncthreads();
  if(threadIdx.x == 0) bsum[blockIdx.x] = red[0]+red[1]+red[2]+red[3];
}

__global__ __launch_bounds__(256) void k_scanB(
    const int* __restrict__ bsum, int* __restrict__ boff){
  __shared__ int ws[4];
  int t = threadIdx.x;
  int x = (t < SCAN_NBLK) ? bsum[t] : 0;
  int lane = t & 63, w = t >> 6;
  int incl = x;
  #pragma unroll
  for(int o=1;o<64;o<<=1){ int v=__shfl_up(incl,o); if(lane>=o) incl+=v; }
  if(lane == 63) ws[w] = incl;
  __syncthreads();
  int pre = 0;
  for(int i=0;i<w;i++) pre += ws[i];
  if(t < SCAN_NBLK) boff[t] = pre + incl - x;
}

__global__ __launch_bounds__(256) void k_scanC(
    const int* __restrict__ counts, const int* __restrict__ boff,
    int* __restrict__ offsets){
  __shared__ int ws[4];
  int idx = blockIdx.x*256 + threadIdx.x;
  int x = (idx < BN_) ? counts[idx] : 0;
  int lane = threadIdx.x & 63, w = threadIdx.x >> 6;
  int incl = x;
  #pragma unroll
  for(int o=1;o<64;o<<=1){ int v=__shfl_up(incl,o); if(lane>=o) incl+=v; }
  if(lane == 63) ws[w] = incl;
  __syncthreads();
  int pre = boff[blockIdx.x];
  for(int i=0;i<w;i++) pre += ws[i];
  int excl = pre + incl - x;
  if(idx < BN_) offsets[idx] = excl;
  if(idx == BN_-1) offsets[BN_] = excl + x;
}

// ------- edge-LN stats prep: M=W W^T, v2=W b, wbar, bbar, s2 (290 floats) -------
__global__ __launch_bounds__(256) void k_eprep(
    const float* __restrict__ W, const float* __restrict__ be,
    float* __restrict__ prep){
  int t = threadIdx.x;
  int i = t >> 4, j = t & 15;
  float m = 0.f;
  for(int c=0;c<256;c++) m += W[i*256+c]*W[j*256+c];
  prep[t] = m;
  if(t < 16){
    float v=0.f, wb=0.f;
    for(int c=0;c<256;c++){ v += W[t*256+c]*be[c]; wb += W[t*256+c]; }
    prep[256+t] = v;
    prep[272+t] = wb*(1.f/256.f);
  }
  if(t == 0){
    float bb=0.f, ss=0.f;
    for(int c=0;c<256;c++){ bb += be[c]; ss += be[c]*be[c]; }
    prep[288] = bb*(1.f/256.f);
    prep[289] = ss;
  }
}

// fill CSR; pre-gather edge features into slot order; compute per-edge LN stats.
__global__ __launch_bounds__(256) void k_fill(
    const int* __restrict__ el, const int* __restrict__ emask,
    const float* __restrict__ ef, const float* __restrict__ prep,
    const int* __restrict__ offsets, int* __restrict__ cursor,
    int* __restrict__ s_send, float* __restrict__ ef_slot,
    float* __restrict__ stats){
  __shared__ float M_s[290];
  for(int i=threadIdx.x; i<290; i+=256) M_s[i] = prep[i];
  __syncthreads();
  int e = blockIdx.x*256 + threadIdx.x;
  if(e >= B_*E_) return;
  if(!emask[e]) return;
  int b = e / E_;
  int s = el[(size_t)e*2], r = el[(size_t)e*2 + 1];
  int bn = b*N_ + r;
  int pos = offsets[bn] + atomicAdd(&cursor[bn], 1);
  s_send[pos] = b*N_ + s;
  const float4* src = reinterpret_cast<const float4*>(ef + (size_t)e*16);
  float4 f0=src[0], f1=src[1], f2=src[2], f3=src[3];
  float4* dst = reinterpret_cast<float4*>(ef_slot + (size_t)pos*16);
  dst[0]=f0; dst[1]=f1; dst[2]=f2; dst[3]=f3;
  float f[16] = {f0.x,f0.y,f0.z,f0.w, f1.x,f1.y,f1.z,f1.w,
                 f2.x,f2.y,f2.z,f2.w, f3.x,f3.y,f3.z,f3.w};
  float mean = M_s[288];
  #pragma unroll
  for(int k=0;k<16;k++) mean += f[k]*M_s[272+k];
  float q = M_s[289];
  #pragma unroll
  for(int i=0;i<16;i++){
    float pi = 2.f*M_s[256+i];
    #pragma unroll
    for(int j=0;j<16;j++) pi += M_s[i*16+j]*f[j];
    q += f[i]*pi;
  }
  float var = q*(1.f/256.f) - mean*mean;
  float rstd = rsqrtf(var + 1e-6f);
  stats[(size_t)pos*2]   = mean;
  stats[(size_t)pos*2+1] = rstd;
}

// ---------------- weights: transpose + bf16: Wt[l][n][k] ----------------
__global__ __launch_bounds__(256) void k_wt(
    const float* __restrict__ gcnW, unsigned short* __restrict__ Wt){
  __shared__ float sm[32][33];
  int bid = blockIdx.x;
  int l = bid >> 7;
  int t = bid & 127;
  int k0 = (t >> 3)*32, n0 = (t & 7)*32;
  int r = threadIdx.x >> 3;
  int c4 = (threadIdx.x & 7)*4;
  const float* src = gcnW + (size_t)l*512*256;
  float4 v = *reinterpret_cast<const float4*>(&src[(size_t)(k0+r)*256 + n0 + c4]);
  sm[r][c4+0]=v.x; sm[r][c4+1]=v.y; sm[r][c4+2]=v.z; sm[r][c4+3]=v.w;
  __syncthreads();
  u16x4 o;
  o.x = f2bf(sm[c4+0][r]); o.y = f2bf(sm[c4+1][r]);
  o.z = f2bf(sm[c4+2][r]); o.w = f2bf(sm[c4+3][r]);
  *reinterpret_cast<u16x4*>(&Wt[(size_t)l*256*512 + (size_t)(n0+r)*512 + k0 + c4]) = o;
}

// ------- edge proj + LN(precomputed stats) + relu, CSR-gathered; no shuffles -------
#define PROJ(F0,F1,F2,F3,COMP) (be4.COMP \
  + F0.x*w[0].COMP + F0.y*w[1].COMP + F0.z*w[2].COMP + F0.w*w[3].COMP \
  + F1.x*w[4].COMP + F1.y*w[5].COMP + F1.z*w[6].COMP + F1.w*w[7].COMP \
  + F2.x*w[8].COMP + F2.y*w[9].COMP + F2.z*w[10].COMP + F2.w*w[11].COMP \
  + F3.x*w[12].COMP + F3.y*w[13].COMP + F3.z*w[14].COMP + F3.w*w[15].COMP)

__global__ __launch_bounds__(256) void k_se_wave(
    const float* __restrict__ ef_slot, const float* __restrict__ stats,
    const float* __restrict__ W, const float* __restrict__ be,
    const float* __restrict__ lns, const float* __restrict__ lnb,
    const int* __restrict__ offsets, unsigned short* __restrict__ Abf){
  int bn = blockIdx.x*4 + (threadIdx.x>>6);
  int lane = threadIdx.x & 63;
  int c = lane*4;
  float4 w[16];
  #pragma unroll
  for(int k=0;k<16;k++) w[k] = *reinterpret_cast<const float4*>(&W[k*D_ + c]);
  float4 be4 = *reinterpret_cast<const float4*>(&be[c]);
  float4 s4  = *reinterpret_cast<const float4*>(&lns[c]);
  float4 b4  = *reinterpret_cast<const float4*>(&lnb[c]);
  int beg = __builtin_amdgcn_readfirstlane(offsets[bn]);
  int end = __builtin_amdgcn_readfirstlane(offsets[bn+1]);
  float a0=0.f,a1=0.f,a2=0.f,a3=0.f;
  int slot = beg;
  for(; slot+2 <= end; slot += 2){
    const float4* e0 = reinterpret_cast<const float4*>(ef_slot + (size_t)slot*16);
    const float4* e1 = reinterpret_cast<const float4*>(ef_slot + (size_t)(slot+1)*16);
    float2 st0 = *reinterpret_cast<const float2*>(stats + (size_t)slot*2);
    float2 st1 = *reinterpret_cast<const float2*>(stats + (size_t)(slot+1)*2);
    float4 f0=e0[0], f1=e0[1], f2=e0[2], f3=e0[3];
    float4 g0=e1[0], g1=e1[1], g2=e1[2], g3=e1[3];
    float t0=PROJ(f0,f1,f2,f3,x), t1=PROJ(f0,f1,f2,f3,y);
    float t2=PROJ(f0,f1,f2,f3,z), t3=PROJ(f0,f1,f2,f3,w);
    float u0=PROJ(g0,g1,g2,g3,x), u1=PROJ(g0,g1,g2,g3,y);
    float u2=PROJ(g0,g1,g2,g3,z), u3=PROJ(g0,g1,g2,g3,w);
    float m0=st0.x, r0=st0.y, m1=st1.x, r1=st1.y;
    a0 += fmaxf((t0-m0)*r0*s4.x + b4.x, 0.f) + fmaxf((u0-m1)*r1*s4.x + b4.x, 0.f);
    a1 += fmaxf((t1-m0)*r0*s4.y + b4.y, 0.f) + fmaxf((u1-m1)*r1*s4.y + b4.y, 0.f);
    a2 += fmaxf((t2-m0)*r0*s4.z + b4.z, 0.f) + fmaxf((u2-m1)*r1*s4.z + b4.z, 0.f);
    a3 += fmaxf((t3-m0)*r0*s4.w + b4.w, 0.f) + fmaxf((u3-m1)*r1*s4.w + b4.w, 0.f);
  }
  if(slot < end){
    const float4* e0 = reinterpret_cast<const float4*>(ef_slot + (size_t)slot*16);
    float2 st0 = *reinterpret_cast<const float2*>(stats + (size_t)slot*2);
    float4 f0=e0[0], f1=e0[1], f2=e0[2], f3=e0[3];
    float t0=PROJ(f0,f1,f2,f3,x), t1=PROJ(f0,f1,f2,f3,y);
    float t2=PROJ(f0,f1,f2,f3,z), t3=PROJ(f0,f1,f2,f3,w);
    float m0=st0.x, r0=st0.y;
    a0 += fmaxf((t0-m0)*r0*s4.x + b4.x, 0.f);
    a1 += fmaxf((t1-m0)*r0*s4.y + b4.y, 0.f);
    a2 += fmaxf((t2-m0)*r0*s4.z + b4.z, 0.f);
    a3 += fmaxf((t3-m0)*r0*s4.w + b4.w, 0.f);
  }
  u16x4 o; o.x=f2bf(a0); o.y=f2bf(a1); o.z=f2bf(a2); o.w=f2bf(a3);
  *reinterpret_cast<u16x4*>(Abf + (size_t)bn*512 + 256 + c) = o;
}

// ---------------- gather-sum senders -> A[:,0:256] (bf16), 4-deep ----------------
__global__ __launch_bounds__(256) void k_agg(
    const unsigned short* __restrict__ hnbf, const int* __restrict__ offsets,
    const int* __restrict__ s_send, unsigned short* __restrict__ Abf){
  int bn = blockIdx.x*4 + (threadIdx.x>>6);
  int lane = threadIdx.x & 63;
  int beg = __builtin_amdgcn_readfirstlane(offsets[bn]);
  int end = __builtin_amdgcn_readfirstlane(offsets[bn+1]);
  float a0=0.f,a1=0.f,a2=0.f,a3=0.f;
  int slot = beg;
  for(; slot+4 <= end; slot += 4){
    int sr0 = s_send[slot],   sr1 = s_send[slot+1];
    int sr2 = s_send[slot+2], sr3 = s_send[slot+3];
    u16x4 v0 = *reinterpret_cast<const u16x4*>(hnbf + (size_t)sr0*D_ + lane*4);
    u16x4 v1 = *reinterpret_cast<const u16x4*>(hnbf + (size_t)sr1*D_ + lane*4);
    u16x4 v2 = *reinterpret_cast<const u16x4*>(hnbf + (size_t)sr2*D_ + lane*4);
    u16x4 v3 = *reinterpret_cast<const u16x4*>(hnbf + (size_t)sr3*D_ + lane*4);
    a0 += bf2f(v0.x)+bf2f(v1.x)+bf2f(v2.x)+bf2f(v3.x);
    a1 += bf2f(v0.y)+bf2f(v1.y)+bf2f(v2.y)+bf2f(v3.y);
    a2 += bf2f(v0.z)+bf2f(v1.z)+bf2f(v2.z)+bf2f(v3.z);
    a3 += bf2f(v0.w)+bf2f(v1.w)+bf2f(v2.w)+bf2f(v3.w);
  }
  for(; slot < end; ++slot){
    int sr = s_send[slot];
    u16x4 v = *reinterpret_cast<const u16x4*>(hnbf + (size_t)sr*D_ + lane*4);
    a0 += bf2f(v.x); a1 += bf2f(v.y); a2 += bf2f(v.z); a3 += bf2f(v.w);
  }
  u16x4 o; o.x=f2bf(a0); o.y=f2bf(a1); o.z=f2bf(a2); o.w=f2bf(a3);
  *reinterpret_cast<u16x4*>(Abf + (size_t)bn*512 + lane*4) = o;
}

// ------- fused GEMM+LN: 128x256 tile, 512 threads (8 waves, 2 row x 4 col).
//         v = hn_in + (A@Wt^T + cnt*bias)/deg; layers 0,1: hn_out=relu(LN(v)) bf16;
//         layer 2 (lnsP==nullptr): h_out = v fp32. -------
__global__ __launch_bounds__(512) void k_gemm_fused(
    const unsigned short* __restrict__ Abf,
    const unsigned short* __restrict__ Wt,
    const float* __restrict__ bias,
    const int* __restrict__ counts,
    const unsigned short* __restrict__ hn_in,
    const float* __restrict__ lnsP, const float* __restrict__ lnbP,
    unsigned short* __restrict__ hn_out,
    float* __restrict__ h_out){
  __shared__ unsigned short A_s[128*32];
  __shared__ unsigned short B_s[256*32];
  __shared__ float red_s[2][4][128];
  int row0 = blockIdx.x * 128;
  int tid = threadIdx.x;
  int lane = tid & 63;
  int w = tid >> 6;
  int wr = w >> 2, wc = w & 3;
  int q = lane >> 4, frow = lane & 15;
  f32x4 acc[4][4];
  #pragma unroll
  for(int m=0;m<4;m++)
    #pragma unroll
    for(int n=0;n<4;n++) acc[m][n] = (f32x4){0.f,0.f,0.f,0.f};

  int ar = tid >> 2, asc = tid & 3;          // A: 128 rows, 1 chunk (8 el) each
  int br = tid >> 1, bsc0 = (tid & 1)*2;     // B: 256 rows, 2 chunks each
  const unsigned short* agp = Abf + (size_t)(row0+ar)*512 + asc*8;
  const unsigned short* bgp = Wt  + (size_t)br*512 + bsc0*8;
  unsigned swA  = (unsigned)(ar*64 + ((asc ^ (ar&3))*16));
  unsigned swB0 = (unsigned)(br*64 + (((bsc0  ) ^ (br&3))*16));
  unsigned swB1 = (unsigned)(br*64 + (((bsc0+1) ^ (br&3))*16));
  int fsw = q ^ (lane & 3);

  for(int k0=0; k0<512; k0+=32){
    short8 av = *reinterpret_cast<const short8*>(agp + k0);
    short8 b0 = *reinterpret_cast<const short8*>(bgp + k0);
    short8 b1 = *reinterpret_cast<const short8*>(bgp + k0 + 8);
    __syncthreads();
    *reinterpret_cast<short8*>((char*)A_s + swA)  = av;
    *reinterpret_cast<short8*>((char*)B_s + swB0) = b0;
    *reinterpret_cast<short8*>((char*)B_s + swB1) = b1;
    __syncthreads();
    short8 af[4], bf[4];
    #pragma unroll
    for(int m=0;m<4;m++){
      int r = wr*64 + m*16 + frow;
      af[m] = *reinterpret_cast<const short8*>((const char*)A_s + r*64 + fsw*16);
    }
    #pragma unroll
    for(int n=0;n<4;n++){
      int cc = wc*64 + n*16 + frow;
      bf[n] = *reinterpret_cast<const short8*>((const char*)B_s + cc*64 + fsw*16);
    }
    #pragma unroll
    for(int m=0;m<4;m++)
      #pragma unroll
      for(int n=0;n<4;n++)
        acc[m][n] = __builtin_amdgcn_mfma_f32_16x16x32_bf16(af[m], bf[n], acc[m][n], 0, 0, 0);
  }

  // epilogue: v = hn + (acc + cnt*bias)/deg; partial row sums -> LDS
  int colbase = wc*64 + frow;
  float bias4[4];
  #pragma unroll
  for(int n=0;n<4;n++) bias4[n] = bias[colbase + n*16];
  #pragma unroll
  for(int m=0;m<4;m++){
    #pragma unroll
    for(int j=0;j<4;j++){
      int rl = wr*64 + m*16 + q*4 + j;
      int row = row0 + rl;
      float cnt = (row < BN_) ? (float)counts[row] : 1.f;
      float inv = 1.f / fmaxf(cnt, 1.f);
      float s = 0.f, s2 = 0.f;
      #pragma unroll
      for(int n=0;n<4;n++){
        int col = colbase + n*16;
        float hv = (row < BN_) ? bf2f(hn_in[(size_t)row*D_ + col]) : 0.f;
        float v = hv + (acc[m][n][j] + cnt*bias4[n])*inv;
        acc[m][n][j] = v;
        s += v; s2 += v*v;
      }
      #pragma unroll
      for(int o=1;o<16;o<<=1){ s += __shfl_xor(s,o); s2 += __shfl_xor(s2,o); }
      if(frow == 0){ red_s[0][wc][rl] = s; red_s[1][wc][rl] = s2; }
    }
  }
  __syncthreads();
  if(lnsP){
    float lns4[4], lnb4[4];
    #pragma unroll
    for(int n=0;n<4;n++){ lns4[n]=lnsP[colbase+n*16]; lnb4[n]=lnbP[colbase+n*16]; }
    #pragma unroll
    for(int m=0;m<4;m++){
      #pragma unroll
      for(int j=0;j<4;j++){
        int rl = wr*64 + m*16 + q*4 + j;
        int row = row0 + rl;
        if(row >= BN_) continue;
        float S  = (red_s[0][0][rl]+red_s[0][1][rl]) + (red_s[0][2][rl]+red_s[0][3][rl]);
        float Q2 = (red_s[1][0][rl]+red_s[1][1][rl]) + (red_s[1][2][rl]+red_s[1][3][rl]);
        float mean = S*(1.f/256.f);
        float var = Q2*(1.f/256.f) - mean*mean;
        float rs = rsqrtf(var + 1e-6f);
        #pragma unroll
        for(int n=0;n<4;n++){
          int col = colbase + n*16;
          float ov = (acc[m][n][j]-mean)*rs*lns4[n] + lnb4[n];
          hn_out[(size_t)row*D_ + col] = f2bf(fmaxf(ov, 0.f));
        }
      }
    }
  } else {
    #pragma unroll
    for(int m=0;m<4;m++){
      #pragma unroll
      for(int j=0;j<4;j++){
        int rl = wr*64 + m*16 + q*4 + j;
        int row = row0 + rl;
        if(row >= BN_) continue;
        #pragma unroll
        for(int n=0;n<4;n++)
          h_out[(size_t)row*D_ + colbase + n*16] = acc[m][n][j];
      }
    }
  }
}

// ---------------- attention prep ----------------
__global__ __launch_bounds__(256) void k_qprep(
    const float* __restrict__ h, const int* __restrict__ agent,
    const float* __restrict__ lnq_s, const float* __restrict__ lnq_b,
    const float* __restrict__ Wq, const float* __restrict__ bq,
    const float* __restrict__ Wk, const float* __restrict__ bk,
    float* __restrict__ q_in, float* __restrict__ Wq_eff,
    float* __restrict__ qconst){
  __shared__ float q_s[256];
  __shared__ float Q_s[256];
  __shared__ float red[4];
  int b = blockIdx.x, c = threadIdx.x;
  size_t row = (size_t)(b*N_ + agent[b]);
  float x = h[row*D_ + c];
  q_in[b*D_ + c] = x;
  float s1 = block_sum(x, red);
  float mean = s1*(1.f/256.f);
  float d = x - mean;
  float s2 = block_sum(d*d, red);
  float q = d * rsqrtf(s2*(1.f/256.f) + 1e-6f) * lnq_s[c] + lnq_b[c];
  q_s[c] = q;
  __syncthreads();
  float acc = bq[c];
  for(int k=0;k<256;k++) acc += q_s[k]*Wq[k*D_ + c];
  Q_s[c] = acc;
  __syncthreads();
  const float scale = 0.17677669529663687f; // 1/sqrt(32)
  for(int idx=c; idx<2048; idx+=256){
    int hh = idx >> 8, dd = idx & 255;
    const float4* wk4 = reinterpret_cast<const float4*>(&Wk[(size_t)dd*D_ + hh*32]);
    const float4* q4  = reinterpret_cast<const float4*>(&Q_s[hh*32]);
    float t = 0.f;
    #pragma unroll
    for(int k4=0;k4<8;k4++){
      float4 w = wk4[k4]; float4 qq = q4[k4];
      t += w.x*qq.x + w.y*qq.y + w.z*qq.z + w.w*qq.w;
    }
    Wq_eff[b*2048 + hh*256 + dd] = t*scale;
  }
  if(c < 8){
    float t = 0.f;
    for(int dh=0; dh<32; dh++) t += Q_s[c*32+dh]*bk[c*32+dh];
    qconst[b*8 + c] = t*scale;
  }
}

// ---------------- k=LN(h) + masked scores (kbuf stored bf16) ----------------
__global__ __launch_bounds__(256) void k_scores(
    const float* __restrict__ h, const float* __restrict__ lnk_s,
    const float* __restrict__ lnk_b, const float* __restrict__ Wq_eff,
    const float* __restrict__ qconst, const int* __restrict__ nmask,
    unsigned short* __restrict__ kbuf, float* __restrict__ scores){
  __shared__ float wq_s[2048];
  int row0 = blockIdx.x * 4;
  int b = row0 / N_;
  for(int i=threadIdx.x; i<2048; i+=256) wq_s[i] = Wq_eff[b*2048 + i];
  __syncthreads();
  int wave = threadIdx.x >> 6, lane = threadIdx.x & 63;
  int row = row0 + wave;
  int n = row - b*N_;
  int c = lane*4;
  float4 x = *reinterpret_cast<const float4*>(&h[(size_t)row*D_ + c]);
  float sum = x.x+x.y+x.z+x.w;
  float sq = x.x*x.x+x.y*x.y+x.z*x.z+x.w*x.w;
  #pragma unroll
  for(int o=32;o>0;o>>=1){ sum += __shfl_xor(sum,o); sq += __shfl_xor(sq,o); }
  float mean = sum*(1.f/256.f);
  float var = sq*(1.f/256.f) - mean*mean;
  float rs = rsqrtf(var + 1e-6f);
  float4 s4 = *reinterpret_cast<const float4*>(&lnk_s[c]);
  float4 b4 = *reinterpret_cast<const float4*>(&lnk_b[c]);
  float4 kv;
  kv.x = (x.x-mean)*rs*s4.x + b4.x;
  kv.y = (x.y-mean)*rs*s4.y + b4.y;
  kv.z = (x.z-mean)*rs*s4.z + b4.z;
  kv.w = (x.w-mean)*rs*s4.w + b4.w;
  u16x4 kb; kb.x=f2bf(kv.x); kb.y=f2bf(kv.y); kb.z=f2bf(kv.z); kb.w=f2bf(kv.w);
  *reinterpret_cast<u16x4*>(&kbuf[(size_t)row*D_ + c]) = kb;
  bool valid = nmask[row] != 0;
  #pragma unroll
  for(int hh=0; hh<8; hh++){
    float4 w = *reinterpret_cast<const float4*>(&wq_s[hh*256 + c]);
    float p = kv.x*w.x + kv.y*w.y + kv.z*w.z + kv.w*w.w;
    p = wave_sum(p);
    if(lane==0) scores[(size_t)(b*8+hh)*N_ + n] = valid ? (p + qconst[b*8+hh]) : -1e9f;
  }
}

// ---------------- softmax stage A: per-chunk max + local sum-exp ----------------
__global__ __launch_bounds__(256) void k_softA(
    const float* __restrict__ scores, float* __restrict__ pm,
    float* __restrict__ ps){
  __shared__ float red[4];
  int bh = blockIdx.x / 10;
  int c0 = (blockIdx.x % 10) * 1000;
  int tid = threadIdx.x;
  float m = -3e38f;
  for(int n=tid; n<1000; n+=256) m = fmaxf(m, scores[(size_t)bh*N_ + c0 + n]);
  #pragma unroll
  for(int o=32;o>0;o>>=1) m = fmaxf(m, __shfl_xor(m,o));
  if((tid&63)==0) red[tid>>6] = m;
  __syncthreads();
  m = fmaxf(fmaxf(red[0],red[1]), fmaxf(red[2],red[3]));
  __syncthreads();
  float s = 0.f;
  for(int n=tid; n<1000; n+=256) s += __expf(scores[(size_t)bh*N_ + c0 + n] - m);
  s = block_sum(s, red);
  if(tid==0){ pm[blockIdx.x] = m; ps[blockIdx.x] = s; }
}

// ---------------- softmax stage B: merge 10 chunks per bh ----------------
__global__ __launch_bounds__(64) void k_softB(
    const float* __restrict__ pm, const float* __restrict__ ps,
    float* __restrict__ mg, float* __restrict__ inv){
  int t = threadIdx.x;
  if(t < 32){
    float m = -3e38f;
    #pragma unroll
    for(int c=0;c<10;c++) m = fmaxf(m, pm[t*10+c]);
    float s = 0.f;
    #pragma unroll
    for(int c=0;c<10;c++) s += ps[t*10+c]*__expf(pm[t*10+c]-m);
    mg[t] = m;
    inv[t] = 1.f/s;
  }
}

// ---------------- kbar: 1000 blocks, 40 rows each; exp on the fly ----------------
__global__ __launch_bounds__(256) void k_kbar(
    const unsigned short* __restrict__ kbuf, const float* __restrict__ scores,
    const float* __restrict__ mg, const float* __restrict__ inv,
    float* __restrict__ kbar){
  __shared__ float p_s[8][40];
  int b = blockIdx.x / 250;
  int n0 = (blockIdx.x % 250) * 40;
  for(int i=threadIdx.x; i<8*40; i+=256){
    int hh = i/40, nn = i - hh*40;
    p_s[hh][nn] = __expf(scores[(size_t)(b*8+hh)*N_ + n0 + nn] - mg[b*8+hh]);
  }
  __syncthreads();
  int c = threadIdx.x;
  float acc[8] = {0.f,0.f,0.f,0.f,0.f,0.f,0.f,0.f};
  for(int nn=0; nn<40; ++nn){
    float kv = bf2f(kbuf[(size_t)(b*N_ + n0 + nn)*D_ + c]);
    #pragma unroll
    for(int hh=0;hh<8;hh++) acc[hh] += p_s[hh][nn]*kv;
  }
  #pragma unroll
  for(int hh=0;hh<8;hh++)
    atomicAdd(&kbar[(b*8+hh)*D_ + c], acc[hh]*inv[b*8+hh]);
}

// ---------------- final ----------------
__global__ __launch_bounds__(256) void k_final(
    const float* __restrict__ kbar, const float* __restrict__ Wv,
    const float* __restrict__ bv, const float* __restrict__ Wo,
    const float* __restrict__ bo, const float* __restrict__ q_in,
    const float* __restrict__ lnf_s, const float* __restrict__ lnf_b,
    float* __restrict__ out){
  __shared__ float kb_s[2048];
  __shared__ float o_s[256];
  __shared__ float red[4];
  int b = blockIdx.x, c = threadIdx.x;
  for(int i=c; i<2048; i+=256) kb_s[i] = kbar[b*2048 + i];
  __syncthreads();
  int hh = c >> 5;
  float o = bv[c];
  for(int d=0; d<256; d++) o += kb_s[hh*256 + d]*Wv[(size_t)d*D_ + c];
  o_s[c] = o;
  __syncthreads();
  float y = bo[c] + q_in[b*D_ + c];
  for(int d=0; d<256; d++) y += o_s[d]*Wo[(size_t)d*D_ + c];
  float s1 = block_sum(y, red);
  float mean = s1*(1.f/256.f);
  float dd = y - mean;
  float s2 = block_sum(dd*dd, red);
  float v = dd * rsqrtf(s2*(1.f/256.f) + 1e-6f) * lnf_s[c] + lnf_b[c];
  out[b*D_ + c] = fmaxf(v, 0.f);
}

extern "C" void kernel_launch(void* const* d_in, const int* in_sizes, int n_in,
                              void* d_out, int out_size, void* d_ws, size_t ws_size,
                              hipStream_t stream){
  const float* nf    = (const float*)d_in[0];
  const float* ef    = (const float*)d_in[1];
  const float* gf    = (const float*)d_in[2];
  const int*   el    = (const int*)d_in[3];
  const int*   emask = (const int*)d_in[4];
  const int*   nmask = (const int*)d_in[5];
  const int*   agent = (const int*)d_in[6];
  const float* W_node = (const float*)d_in[7];
  const float* b_node = (const float*)d_in[8];
  const float* W_edge = (const float*)d_in[9];
  const float* b_edge = (const float*)d_in[10];
  const float* ln_e_s = (const float*)d_in[11];
  const float* ln_e_b = (const float*)d_in[12];
  const float* gcn_W  = (const float*)d_in[13];
  const float* gcn_b  = (const float*)d_in[14];
  const float* ln_s   = (const float*)d_in[15];
  const float* ln_b   = (const float*)d_in[16];
  const float* lnq_s  = (const float*)d_in[17];
  const float* lnq_b  = (const float*)d_in[18];
  const float* lnk_s  = (const float*)d_in[19];
  const float* lnk_b  = (const float*)d_in[20];
  const float* Wq = (const float*)d_in[21];
  const float* bq = (const float*)d_in[22];
  const float* Wk = (const float*)d_in[23];
  const float* bk = (const float*)d_in[24];
  const float* Wv = (const float*)d_in[25];
  const float* bv = (const float*)d_in[26];
  const float* Wo = (const float*)d_in[27];
  const float* bo = (const float*)d_in[28];
  const float* lnf_s = (const float*)d_in[29];
  const float* lnf_b = (const float*)d_in[30];
  float* out = (float*)d_out;

  const size_t ND = (size_t)BN_*D_;
  char* w = (char*)d_ws;
  float* h_buf = (float*)w;                   w += ND*4;
  unsigned short* hnA = (unsigned short*)w;   w += (size_t)MPAD*D_*2;
  unsigned short* hnB = (unsigned short*)w;   w += (size_t)MPAD*D_*2;
  unsigned short* A_bf = (unsigned short*)w;  w += (size_t)MPAD*512*2;
  unsigned short* Wt = (unsigned short*)w;    w += (size_t)3*256*512*2;
  float* scores = (float*)w;                  w += (size_t)B_*8*N_*4;
  float* q_in = (float*)w;                    w += B_*D_*4;
  float* Wq_eff = (float*)w;                  w += B_*8*D_*4;
  float* qconst = (float*)w;                  w += B_*8*4;
  float* pm = (float*)w;                      w += 320*4;
  float* ps = (float*)w;                      w += 320*4;
  float* mg = (float*)w;                      w += 32*4;
  float* invs = (float*)w;                    w += 32*4;
  float* kbar = (float*)w;                    w += B_*8*D_*4;
  float* prep = (float*)w;                    w += 512*4;
  int* counts = (int*)w;                      w += BN_*4;
  int* cursor = (int*)w;                      w += BN_*4;
  int* offsets = (int*)w;                     w += (BN_+1)*4;
  int* bsum = (int*)w;                        w += SCAN_NBLK*4;
  int* boff = (int*)w;                        w += SCAN_NBLK*4;
  int* s_send = (int*)w;                      w += (size_t)B_*E_*4;
  float* ef_slot = (float*)w;                 w += (size_t)B_*E_*16*4;
  float* stats = (float*)w;                   w += (size_t)B_*E_*2*4;
  unsigned short* kbuf = (unsigned short*)A_bf; // A dead after layers; reuse

  hipMemsetAsync(counts, 0, sizeof(int)*(size_t)2*BN_, stream);   // counts+cursor
  hipMemsetAsync(kbar, 0, sizeof(float)*(size_t)B_*8*D_, stream);

  k_node_in<<<BN_/16, 256, 0, stream>>>(nf, gf, W_node, b_node, ln_s, ln_b, hnA);
  k_hist<<<B_*E_/256, 256, 0, stream>>>(el, emask, counts);
  k_scanA<<<SCAN_NBLK, 256, 0, stream>>>(counts, bsum);
  k_scanB<<<1, 256, 0, stream>>>(bsum, boff);
  k_scanC<<<SCAN_NBLK, 256, 0, stream>>>(counts, boff, offsets);
  k_eprep<<<1, 256, 0, stream>>>(W_edge, b_edge, prep);
  k_fill<<<B_*E_/256, 256, 0, stream>>>(el, emask, ef, prep, offsets, cursor,
                                        s_send, ef_slot, stats);
  k_wt<<<384, 256, 0, stream>>>(gcn_W, Wt);
  k_se_wave<<<BN_/4, 256, 0, stream>>>(ef_slot, stats, W_edge, b_edge,
                                       ln_e_s, ln_e_b, offsets, A_bf);

  unsigned short* hin = hnA;
  unsigned short* hout = hnB;
  for(int i=0;i<3;i++){
    k_agg<<<BN_/4, 256, 0, stream>>>(hin, offsets, s_send, A_bf);
    const float* lp = (i<2) ? (ln_s + (i+1)*D_) : nullptr;
    const float* lb = (i<2) ? (ln_b + (i+1)*D_) : nullptr;
    k_gemm_fused<<<MPAD/128, 512, 0, stream>>>(A_bf, Wt + (size_t)i*256*512,
                                               gcn_b + i*D_, counts, hin,
                                               lp, lb, hout, h_buf);
    unsigned short* t = hin; hin = hout; hout = t;
  }

  k_qprep<<<B_, 256, 0, stream>>>(h_buf, agent, lnq_s, lnq_b, Wq, bq, Wk, bk,
                                  q_in, Wq_eff, qconst);
  k_scores<<<BN_/4, 256, 0, stream>>>(h_buf, lnk_s, lnk_b, Wq_eff, qconst, nmask,
                                      kbuf, scores);
  k_softA<<<320, 256, 0, stream>>>(scores, pm, ps);
  k_softB<<<1, 64, 0, stream>>>(pm, ps, mg, invs);
  k_kbar<<<B_*250, 256, 0, stream>>>(kbuf, scores, mg, invs, kbar);
  k_final<<<B_, 256, 0, stream>>>(kbar, Wv, bv, Wo, bo, q_in, lnf_s, lnf_b, out);
}

// Round 13
// 483.960 us; speedup vs baseline: 1.1040x; 1.1040x over previous
//
#include <hip/hip_runtime.h>
#include <hip/hip_bf16.h>

#define B_ 4
#define N_ 10000
#define E_ 80000
#define D_ 256
#define BN_ (B_*N_)
#define MPAD 40064
#define SCAN_NBLK ((BN_ + 255) / 256)

typedef __attribute__((ext_vector_type(8))) short short8;
typedef __attribute__((ext_vector_type(4))) float f32x4;
typedef __attribute__((ext_vector_type(4))) unsigned short u16x4;

static __device__ __forceinline__ float wave_sum(float v){
  #pragma unroll
  for(int o=32;o>0;o>>=1) v += __shfl_xor(v, o);
  return v;
}

static __device__ __forceinline__ float block_sum(float v, float* red){
  v = wave_sum(v);
  int w = threadIdx.x >> 6;
  if((threadIdx.x & 63) == 0) red[w] = v;
  __syncthreads();
  float r = (red[0] + red[1]) + (red[2] + red[3]);
  __syncthreads();
  return r;
}

static __device__ __forceinline__ unsigned short f2bf(float f){
  unsigned u = __float_as_uint(f);
  return (unsigned short)((u + 0x7fffu + ((u>>16)&1u)) >> 16);
}
static __device__ __forceinline__ float bf2f(unsigned short b){
  return __uint_as_float(((unsigned)b) << 16);
}

// ------- node input projection + LN0 + relu -> hn0 (bf16) -------
__global__ __launch_bounds__(256) void k_node_in(
    const float* __restrict__ nf, const float* __restrict__ gf,
    const float* __restrict__ W, const float* __restrict__ bias,
    const float* __restrict__ lns, const float* __restrict__ lnb,
    unsigned short* __restrict__ hnbf){
  __shared__ float in_s[16][96];
  __shared__ float h_s[16][256];
  int base = blockIdx.x * 16;
  int tid = threadIdx.x;
  for(int idx = tid; idx < 16*96; idx += 256){
    int i = idx / 96, k = idx - i*96;
    int row = base + i;
    int b = row / N_;
    float v = (k < 64) ? nf[(size_t)row*64 + k] : gf[b*32 + (k-64)];
    in_s[i][k] = v;
  }
  __syncthreads();
  int c = tid;
  float acc[16];
  #pragma unroll
  for(int i=0;i<16;i++) acc[i]=0.f;
  for(int k=0;k<96;k+=4){
    float w0 = W[(k+0)*D_+c], w1 = W[(k+1)*D_+c];
    float w2 = W[(k+2)*D_+c], w3 = W[(k+3)*D_+c];
    #pragma unroll
    for(int i=0;i<16;i++){
      float4 a = *reinterpret_cast<const float4*>(&in_s[i][k]);
      acc[i] += a.x*w0 + a.y*w1 + a.z*w2 + a.w*w3;
    }
  }
  float bc = bias[c];
  #pragma unroll
  for(int i=0;i<16;i++) h_s[i][c] = acc[i] + bc;
  __syncthreads();
  int wv = tid>>6, lane = tid&63;
  float4 s4 = *reinterpret_cast<const float4*>(&lns[lane*4]);
  float4 b4 = *reinterpret_cast<const float4*>(&lnb[lane*4]);
  #pragma unroll
  for(int rr=0; rr<4; ++rr){
    int i = wv*4 + rr;
    float4 x = *reinterpret_cast<const float4*>(&h_s[i][lane*4]);
    float sum = x.x+x.y+x.z+x.w;
    float sq = x.x*x.x+x.y*x.y+x.z*x.z+x.w*x.w;
    #pragma unroll
    for(int o=32;o>0;o>>=1){ sum += __shfl_xor(sum,o); sq += __shfl_xor(sq,o); }
    float mean = sum*(1.f/256.f);
    float var = sq*(1.f/256.f) - mean*mean;
    float rs = rsqrtf(var + 1e-6f);
    u16x4 o;
    o.x = f2bf(fmaxf((x.x-mean)*rs*s4.x + b4.x, 0.f));
    o.y = f2bf(fmaxf((x.y-mean)*rs*s4.y + b4.y, 0.f));
    o.z = f2bf(fmaxf((x.z-mean)*rs*s4.z + b4.z, 0.f));
    o.w = f2bf(fmaxf((x.w-mean)*rs*s4.w + b4.w, 0.f));
    *reinterpret_cast<u16x4*>(&hnbf[(size_t)(base+i)*D_ + lane*4]) = o;
  }
}

// ---------------- CSR build ----------------
__global__ __launch_bounds__(256) void k_hist(
    const int* __restrict__ el, const int* __restrict__ emask,
    int* __restrict__ counts){
  int e = blockIdx.x*256 + threadIdx.x;
  if(e >= B_*E_) return;
  if(emask[e]){
    int b = e / E_;
    int r = el[(size_t)e*2 + 1];
    atomicAdd(&counts[b*N_ + r], 1);
  }
}

// ---- multi-block exclusive scan of counts[BN_] -> offsets[BN_+1] ----
__global__ __launch_bounds__(256) void k_scanA(
    const int* __restrict__ counts, int* __restrict__ bsum){
  __shared__ int red[4];
  int idx = blockIdx.x*256 + threadIdx.x;
  int x = (idx < BN_) ? counts[idx] : 0;
  int lane = threadIdx.x & 63, w = threadIdx.x >> 6;
  int s = x;
  #pragma unroll
  for(int o=32;o>0;o>>=1) s += __shfl_xor(s, o);
  if(lane == 0) red[w] = s;
  __syncthreads();
  if(threadIdx.x == 0) bsum[blockIdx.x] = red[0]+red[1]+red[2]+red[3];
}

// block 0: scan of block sums; block 1: edge-LN stats prep (290 floats)
__global__ __launch_bounds__(256) void k_scanB_eprep(
    const int* __restrict__ bsum, int* __restrict__ boff,
    const float* __restrict__ W, const float* __restrict__ be,
    float* __restrict__ prep){
  if(blockIdx.x == 0){
    __shared__ int ws[4];
    int t = threadIdx.x;
    int x = (t < SCAN_NBLK) ? bsum[t] : 0;
    int lane = t & 63, w = t >> 6;
    int incl = x;
    #pragma unroll
    for(int o=1;o<64;o<<=1){ int v=__shfl_up(incl,o); if(lane>=o) incl+=v; }
    if(lane == 63) ws[w] = incl;
    __syncthreads();
    int pre = 0;
    for(int i=0;i<w;i++) pre += ws[i];
    if(t < SCAN_NBLK) boff[t] = pre + incl - x;
  } else {
    int t = threadIdx.x;
    int i = t >> 4, j = t & 15;
    float m = 0.f;
    for(int c=0;c<256;c++) m += W[i*256+c]*W[j*256+c];
    prep[t] = m;
    if(t < 16){
      float v=0.f, wb=0.f;
      for(int c=0;c<256;c++){ v += W[t*256+c]*be[c]; wb += W[t*256+c]; }
      prep[256+t] = v;
      prep[272+t] = wb*(1.f/256.f);
    }
    if(t == 0){
      float bb=0.f, ss=0.f;
      for(int c=0;c<256;c++){ bb += be[c]; ss += be[c]*be[c]; }
      prep[288] = bb*(1.f/256.f);
      prep[289] = ss;
    }
  }
}

__global__ __launch_bounds__(256) void k_scanC(
    const int* __restrict__ counts, const int* __restrict__ boff,
    int* __restrict__ offsets){
  __shared__ int ws[4];
  int idx = blockIdx.x*256 + threadIdx.x;
  int x = (idx < BN_) ? counts[idx] : 0;
  int lane = threadIdx.x & 63, w = threadIdx.x >> 6;
  int incl = x;
  #pragma unroll
  for(int o=1;o<64;o<<=1){ int v=__shfl_up(incl,o); if(lane>=o) incl+=v; }
  if(lane == 63) ws[w] = incl;
  __syncthreads();
  int pre = boff[blockIdx.x];
  for(int i=0;i<w;i++) pre += ws[i];
  int excl = pre + incl - x;
  if(idx < BN_) offsets[idx] = excl;
  if(idx == BN_-1) offsets[BN_] = excl + x;
}

// fill CSR; pre-gather edge features into slot order; compute per-edge LN stats.
__global__ __launch_bounds__(256) void k_fill(
    const int* __restrict__ el, const int* __restrict__ emask,
    const float* __restrict__ ef, const float* __restrict__ prep,
    const int* __restrict__ offsets, int* __restrict__ cursor,
    int* __restrict__ s_send, float* __restrict__ ef_slot,
    float* __restrict__ stats){
  __shared__ float M_s[290];
  for(int i=threadIdx.x; i<290; i+=256) M_s[i] = prep[i];
  __syncthreads();
  int e = blockIdx.x*256 + threadIdx.x;
  if(e >= B_*E_) return;
  if(!emask[e]) return;
  int b = e / E_;
  int s = el[(size_t)e*2], r = el[(size_t)e*2 + 1];
  int bn = b*N_ + r;
  int pos = offsets[bn] + atomicAdd(&cursor[bn], 1);
  s_send[pos] = b*N_ + s;
  const float4* src = reinterpret_cast<const float4*>(ef + (size_t)e*16);
  float4 f0=src[0], f1=src[1], f2=src[2], f3=src[3];
  float4* dst = reinterpret_cast<float4*>(ef_slot + (size_t)pos*16);
  dst[0]=f0; dst[1]=f1; dst[2]=f2; dst[3]=f3;
  float f[16] = {f0.x,f0.y,f0.z,f0.w, f1.x,f1.y,f1.z,f1.w,
                 f2.x,f2.y,f2.z,f2.w, f3.x,f3.y,f3.z,f3.w};
  float mean = M_s[288];
  #pragma unroll
  for(int k=0;k<16;k++) mean += f[k]*M_s[272+k];
  float q = M_s[289];
  #pragma unroll
  for(int i=0;i<16;i++){
    float pi = 2.f*M_s[256+i];
    #pragma unroll
    for(int j=0;j<16;j++) pi += M_s[i*16+j]*f[j];
    q += f[i]*pi;
  }
  float var = q*(1.f/256.f) - mean*mean;
  float rstd = rsqrtf(var + 1e-6f);
  stats[(size_t)pos*2]   = mean;
  stats[(size_t)pos*2+1] = rstd;
}

// ---------------- weights: transpose + bf16: Wt[l][n][k] ----------------
__global__ __launch_bounds__(256) void k_wt(
    const float* __restrict__ gcnW, unsigned short* __restrict__ Wt){
  __shared__ float sm[32][33];
  int bid = blockIdx.x;
  int l = bid >> 7;
  int t = bid & 127;
  int k0 = (t >> 3)*32, n0 = (t & 7)*32;
  int r = threadIdx.x >> 3;
  int c4 = (threadIdx.x & 7)*4;
  const float* src = gcnW + (size_t)l*512*256;
  float4 v = *reinterpret_cast<const float4*>(&src[(size_t)(k0+r)*256 + n0 + c4]);
  sm[r][c4+0]=v.x; sm[r][c4+1]=v.y; sm[r][c4+2]=v.z; sm[r][c4+3]=v.w;
  __syncthreads();
  u16x4 o;
  o.x = f2bf(sm[c4+0][r]); o.y = f2bf(sm[c4+1][r]);
  o.z = f2bf(sm[c4+2][r]); o.w = f2bf(sm[c4+3][r]);
  *reinterpret_cast<u16x4*>(&Wt[(size_t)l*256*512 + (size_t)(n0+r)*512 + k0 + c4]) = o;
}

// ------- edge proj + LN(precomputed stats) + relu, CSR-gathered; no shuffles -------
#define PROJ(F0,F1,F2,F3,COMP) (be4.COMP \
  + F0.x*w[0].COMP + F0.y*w[1].COMP + F0.z*w[2].COMP + F0.w*w[3].COMP \
  + F1.x*w[4].COMP + F1.y*w[5].COMP + F1.z*w[6].COMP + F1.w*w[7].COMP \
  + F2.x*w[8].COMP + F2.y*w[9].COMP + F2.z*w[10].COMP + F2.w*w[11].COMP \
  + F3.x*w[12].COMP + F3.y*w[13].COMP + F3.z*w[14].COMP + F3.w*w[15].COMP)

__global__ __launch_bounds__(256) void k_se_wave(
    const float* __restrict__ ef_slot, const float* __restrict__ stats,
    const float* __restrict__ W, const float* __restrict__ be,
    const float* __restrict__ lns, const float* __restrict__ lnb,
    const int* __restrict__ offsets, unsigned short* __restrict__ Abf){
  int bn = blockIdx.x*4 + (threadIdx.x>>6);
  int lane = threadIdx.x & 63;
  int c = lane*4;
  float4 w[16];
  #pragma unroll
  for(int k=0;k<16;k++) w[k] = *reinterpret_cast<const float4*>(&W[k*D_ + c]);
  float4 be4 = *reinterpret_cast<const float4*>(&be[c]);
  float4 s4  = *reinterpret_cast<const float4*>(&lns[c]);
  float4 b4  = *reinterpret_cast<const float4*>(&lnb[c]);
  int beg = __builtin_amdgcn_readfirstlane(offsets[bn]);
  int end = __builtin_amdgcn_readfirstlane(offsets[bn+1]);
  float a0=0.f,a1=0.f,a2=0.f,a3=0.f;
  int slot = beg;
  for(; slot+2 <= end; slot += 2){
    const float4* e0 = reinterpret_cast<const float4*>(ef_slot + (size_t)slot*16);
    const float4* e1 = reinterpret_cast<const float4*>(ef_slot + (size_t)(slot+1)*16);
    float2 st0 = *reinterpret_cast<const float2*>(stats + (size_t)slot*2);
    float2 st1 = *reinterpret_cast<const float2*>(stats + (size_t)(slot+1)*2);
    float4 f0=e0[0], f1=e0[1], f2=e0[2], f3=e0[3];
    float4 g0=e1[0], g1=e1[1], g2=e1[2], g3=e1[3];
    float t0=PROJ(f0,f1,f2,f3,x), t1=PROJ(f0,f1,f2,f3,y);
    float t2=PROJ(f0,f1,f2,f3,z), t3=PROJ(f0,f1,f2,f3,w);
    float u0=PROJ(g0,g1,g2,g3,x), u1=PROJ(g0,g1,g2,g3,y);
    float u2=PROJ(g0,g1,g2,g3,z), u3=PROJ(g0,g1,g2,g3,w);
    float m0=st0.x, r0=st0.y, m1=st1.x, r1=st1.y;
    a0 += fmaxf((t0-m0)*r0*s4.x + b4.x, 0.f) + fmaxf((u0-m1)*r1*s4.x + b4.x, 0.f);
    a1 += fmaxf((t1-m0)*r0*s4.y + b4.y, 0.f) + fmaxf((u1-m1)*r1*s4.y + b4.y, 0.f);
    a2 += fmaxf((t2-m0)*r0*s4.z + b4.z, 0.f) + fmaxf((u2-m1)*r1*s4.z + b4.z, 0.f);
    a3 += fmaxf((t3-m0)*r0*s4.w + b4.w, 0.f) + fmaxf((u3-m1)*r1*s4.w + b4.w, 0.f);
  }
  if(slot < end){
    const float4* e0 = reinterpret_cast<const float4*>(ef_slot + (size_t)slot*16);
    float2 st0 = *reinterpret_cast<const float2*>(stats + (size_t)slot*2);
    float4 f0=e0[0], f1=e0[1], f2=e0[2], f3=e0[3];
    float t0=PROJ(f0,f1,f2,f3,x), t1=PROJ(f0,f1,f2,f3,y);
    float t2=PROJ(f0,f1,f2,f3,z), t3=PROJ(f0,f1,f2,f3,w);
    float m0=st0.x, r0=st0.y;
    a0 += fmaxf((t0-m0)*r0*s4.x + b4.x, 0.f);
    a1 += fmaxf((t1-m0)*r0*s4.y + b4.y, 0.f);
    a2 += fmaxf((t2-m0)*r0*s4.z + b4.z, 0.f);
    a3 += fmaxf((t3-m0)*r0*s4.w + b4.w, 0.f);
  }
  u16x4 o; o.x=f2bf(a0); o.y=f2bf(a1); o.z=f2bf(a2); o.w=f2bf(a3);
  *reinterpret_cast<u16x4*>(Abf + (size_t)bn*512 + 256 + c) = o;
}

// ---------------- LN + relu -> hn (bf16) ----------------
__global__ __launch_bounds__(256) void k_ln_relu(
    const float* __restrict__ h, const float* __restrict__ s,
    const float* __restrict__ b, unsigned short* __restrict__ hnbf){
  int row = blockIdx.x*4 + (threadIdx.x>>6);
  int lane = threadIdx.x & 63;
  int c = lane*4;
  float4 x = *reinterpret_cast<const float4*>(&h[(size_t)row*D_ + c]);
  float sum = x.x+x.y+x.z+x.w;
  float sq = x.x*x.x+x.y*x.y+x.z*x.z+x.w*x.w;
  #pragma unroll
  for(int o=32;o>0;o>>=1){ sum += __shfl_xor(sum,o); sq += __shfl_xor(sq,o); }
  float mean = sum*(1.f/256.f);
  float var = sq*(1.f/256.f) - mean*mean;
  float rs = rsqrtf(var + 1e-6f);
  float4 s4 = *reinterpret_cast<const float4*>(&s[c]);
  float4 b4 = *reinterpret_cast<const float4*>(&b[c]);
  u16x4 o;
  o.x = f2bf(fmaxf((x.x-mean)*rs*s4.x + b4.x, 0.f));
  o.y = f2bf(fmaxf((x.y-mean)*rs*s4.y + b4.y, 0.f));
  o.z = f2bf(fmaxf((x.z-mean)*rs*s4.z + b4.z, 0.f));
  o.w = f2bf(fmaxf((x.w-mean)*rs*s4.w + b4.w, 0.f));
  *reinterpret_cast<u16x4*>(&hnbf[(size_t)row*D_ + c]) = o;
}

// ---------------- gather-sum senders -> A[:,0:256] (bf16), 4-deep ----------------
__global__ __launch_bounds__(256) void k_agg(
    const unsigned short* __restrict__ hnbf, const int* __restrict__ offsets,
    const int* __restrict__ s_send, unsigned short* __restrict__ Abf){
  int bn = blockIdx.x*4 + (threadIdx.x>>6);
  int lane = threadIdx.x & 63;
  int beg = __builtin_amdgcn_readfirstlane(offsets[bn]);
  int end = __builtin_amdgcn_readfirstlane(offsets[bn+1]);
  float a0=0.f,a1=0.f,a2=0.f,a3=0.f;
  int slot = beg;
  for(; slot+4 <= end; slot += 4){
    int sr0 = s_send[slot],   sr1 = s_send[slot+1];
    int sr2 = s_send[slot+2], sr3 = s_send[slot+3];
    u16x4 v0 = *reinterpret_cast<const u16x4*>(hnbf + (size_t)sr0*D_ + lane*4);
    u16x4 v1 = *reinterpret_cast<const u16x4*>(hnbf + (size_t)sr1*D_ + lane*4);
    u16x4 v2 = *reinterpret_cast<const u16x4*>(hnbf + (size_t)sr2*D_ + lane*4);
    u16x4 v3 = *reinterpret_cast<const u16x4*>(hnbf + (size_t)sr3*D_ + lane*4);
    a0 += bf2f(v0.x)+bf2f(v1.x)+bf2f(v2.x)+bf2f(v3.x);
    a1 += bf2f(v0.y)+bf2f(v1.y)+bf2f(v2.y)+bf2f(v3.y);
    a2 += bf2f(v0.z)+bf2f(v1.z)+bf2f(v2.z)+bf2f(v3.z);
    a3 += bf2f(v0.w)+bf2f(v1.w)+bf2f(v2.w)+bf2f(v3.w);
  }
  for(; slot < end; ++slot){
    int sr = s_send[slot];
    u16x4 v = *reinterpret_cast<const u16x4*>(hnbf + (size_t)sr*D_ + lane*4);
    a0 += bf2f(v.x); a1 += bf2f(v.y); a2 += bf2f(v.z); a3 += bf2f(v.w);
  }
  u16x4 o; o.x=f2bf(a0); o.y=f2bf(a1); o.z=f2bf(a2); o.w=f2bf(a3);
  *reinterpret_cast<u16x4*>(Abf + (size_t)bn*512 + lane*4) = o;
}

// ---------------- MFMA GEMM: v = hn + (A@Wt^T + cnt*bias)/deg ----------------
// layers 0,1: hout fp32 (for ln_relu); layer 2: hout_bf bf16 (attention input).
__global__ __launch_bounds__(256) void k_gemm_mfma(
    const unsigned short* __restrict__ Abf,
    const unsigned short* __restrict__ Wt,
    const float* __restrict__ bias,
    const int* __restrict__ counts,
    const unsigned short* __restrict__ hnbf,
    float* __restrict__ hout,
    unsigned short* __restrict__ hout_bf){
  __shared__ unsigned short A_s[128*32];
  __shared__ unsigned short B_s[128*32];
  int bid = blockIdx.x;
  int row0 = (bid>>1)*128;
  int col0 = (bid&1)*128;
  int tid = threadIdx.x;
  int lane = tid & 63;
  int wid = tid >> 6;
  int wr = wid >> 1, wc = wid & 1;
  f32x4 acc[4][4];
  #pragma unroll
  for(int m=0;m<4;m++)
    #pragma unroll
    for(int n=0;n<4;n++) acc[m][n] = (f32x4){0.f,0.f,0.f,0.f};

  int sr = tid >> 1;
  int sc0 = (tid & 1)*2;
  const unsigned short* agp = Abf + (size_t)(row0+sr)*512;
  const unsigned short* bgp = Wt  + (size_t)(col0+sr)*512;
  unsigned swA0 = (unsigned)(sr*64 + (((sc0  ) ^ (sr&3))*16));
  unsigned swA1 = (unsigned)(sr*64 + (((sc0+1) ^ (sr&3))*16));
  int frow = lane & 15;
  int fsw = (lane >> 4) ^ (lane & 3);

  for(int k0=0; k0<512; k0+=32){
    short8 a0 = *reinterpret_cast<const short8*>(agp + k0 + sc0*8);
    short8 a1 = *reinterpret_cast<const short8*>(agp + k0 + sc0*8 + 8);
    short8 b0 = *reinterpret_cast<const short8*>(bgp + k0 + sc0*8);
    short8 b1 = *reinterpret_cast<const short8*>(bgp + k0 + sc0*8 + 8);
    __syncthreads();
    *reinterpret_cast<short8*>((char*)A_s + swA0) = a0;
    *reinterpret_cast<short8*>((char*)A_s + swA1) = a1;
    *reinterpret_cast<short8*>((char*)B_s + swA0) = b0;
    *reinterpret_cast<short8*>((char*)B_s + swA1) = b1;
    __syncthreads();
    short8 af[4], bfr[4];
    #pragma unroll
    for(int m=0;m<4;m++){
      int r = wr*64 + m*16 + frow;
      af[m] = *reinterpret_cast<const short8*>((const char*)A_s + r*64 + fsw*16);
    }
    #pragma unroll
    for(int n=0;n<4;n++){
      int r = wc*64 + n*16 + frow;
      bfr[n] = *reinterpret_cast<const short8*>((const char*)B_s + r*64 + fsw*16);
    }
    #pragma unroll
    for(int m=0;m<4;m++)
      #pragma unroll
      for(int n=0;n<4;n++)
        acc[m][n] = __builtin_amdgcn_mfma_f32_16x16x32_bf16(af[m], bfr[n], acc[m][n], 0, 0, 0);
  }
  #pragma unroll
  for(int m=0;m<4;m++){
    #pragma unroll
    for(int n=0;n<4;n++){
      int col = col0 + wc*64 + n*16 + (lane&15);
      int rbase = row0 + wr*64 + m*16 + (lane>>4)*4;
      float bcol = bias[col];
      #pragma unroll
      for(int j=0;j<4;j++){
        int r = rbase + j;
        if(r < BN_){
          float cnt = (float)counts[r];
          float inv = 1.f / fmaxf(cnt, 1.f);
          float v = bf2f(hnbf[(size_t)r*D_ + col]) + (acc[m][n][j] + cnt*bcol)*inv;
          if(hout_bf) hout_bf[(size_t)r*D_ + col] = f2bf(v);
          else        hout[(size_t)r*D_ + col] = v;
        }
      }
    }
  }
}

// ---------------- attention prep (h in bf16) ----------------
__global__ __launch_bounds__(256) void k_qprep(
    const unsigned short* __restrict__ hb, const int* __restrict__ agent,
    const float* __restrict__ lnq_s, const float* __restrict__ lnq_b,
    const float* __restrict__ Wq, const float* __restrict__ bq,
    const float* __restrict__ Wk, const float* __restrict__ bk,
    float* __restrict__ q_in, float* __restrict__ Wq_eff,
    float* __restrict__ qconst){
  __shared__ float q_s[256];
  __shared__ float Q_s[256];
  __shared__ float red[4];
  int b = blockIdx.x, c = threadIdx.x;
  size_t row = (size_t)(b*N_ + agent[b]);
  float x = bf2f(hb[row*D_ + c]);
  q_in[b*D_ + c] = x;
  float s1 = block_sum(x, red);
  float mean = s1*(1.f/256.f);
  float d = x - mean;
  float s2 = block_sum(d*d, red);
  float q = d * rsqrtf(s2*(1.f/256.f) + 1e-6f) * lnq_s[c] + lnq_b[c];
  q_s[c] = q;
  __syncthreads();
  float acc = bq[c];
  for(int k=0;k<256;k++) acc += q_s[k]*Wq[k*D_ + c];
  Q_s[c] = acc;
  __syncthreads();
  const float scale = 0.17677669529663687f; // 1/sqrt(32)
  for(int idx=c; idx<2048; idx+=256){
    int hh = idx >> 8, dd = idx & 255;
    const float4* wk4 = reinterpret_cast<const float4*>(&Wk[(size_t)dd*D_ + hh*32]);
    const float4* q4  = reinterpret_cast<const float4*>(&Q_s[hh*32]);
    float t = 0.f;
    #pragma unroll
    for(int k4=0;k4<8;k4++){
      float4 w = wk4[k4]; float4 qq = q4[k4];
      t += w.x*qq.x + w.y*qq.y + w.z*qq.z + w.w*qq.w;
    }
    Wq_eff[b*2048 + hh*256 + dd] = t*scale;
  }
  if(c < 8){
    float t = 0.f;
    for(int dh=0; dh<32; dh++) t += Q_s[c*32+dh]*bk[c*32+dh];
    qconst[b*8 + c] = t*scale;
  }
}

// ---------------- k=LN(h bf16) + masked scores (kbuf stored bf16) ----------------
__global__ __launch_bounds__(256) void k_scores(
    const unsigned short* __restrict__ hb, const float* __restrict__ lnk_s,
    const float* __restrict__ lnk_b, const float* __restrict__ Wq_eff,
    const float* __restrict__ qconst, const int* __restrict__ nmask,
    unsigned short* __restrict__ kbuf, float* __restrict__ scores){
  __shared__ float wq_s[2048];
  int row0 = blockIdx.x * 4;
  int b = row0 / N_;
  for(int i=threadIdx.x; i<2048; i+=256) wq_s[i] = Wq_eff[b*2048 + i];
  __syncthreads();
  int wave = threadIdx.x >> 6, lane = threadIdx.x & 63;
  int row = row0 + wave;
  int n = row - b*N_;
  int c = lane*4;
  u16x4 xv = *reinterpret_cast<const u16x4*>(hb + (size_t)row*D_ + c);
  float4 x; x.x=bf2f(xv.x); x.y=bf2f(xv.y); x.z=bf2f(xv.z); x.w=bf2f(xv.w);
  float sum = x.x+x.y+x.z+x.w;
  float sq = x.x*x.x+x.y*x.y+x.z*x.z+x.w*x.w;
  #pragma unroll
  for(int o=32;o>0;o>>=1){ sum += __shfl_xor(sum,o); sq += __shfl_xor(sq,o); }
  float mean = sum*(1.f/256.f);
  float var = sq*(1.f/256.f) - mean*mean;
  float rs = rsqrtf(var + 1e-6f);
  float4 s4 = *reinterpret_cast<const float4*>(&lnk_s[c]);
  float4 b4 = *reinterpret_cast<const float4*>(&lnk_b[c]);
  float4 kv;
  kv.x = (x.x-mean)*rs*s4.x + b4.x;
  kv.y = (x.y-mean)*rs*s4.y + b4.y;
  kv.z = (x.z-mean)*rs*s4.z + b4.z;
  kv.w = (x.w-mean)*rs*s4.w + b4.w;
  u16x4 kb; kb.x=f2bf(kv.x); kb.y=f2bf(kv.y); kb.z=f2bf(kv.z); kb.w=f2bf(kv.w);
  *reinterpret_cast<u16x4*>(&kbuf[(size_t)row*D_ + c]) = kb;
  bool valid = nmask[row] != 0;
  #pragma unroll
  for(int hh=0; hh<8; hh++){
    float4 w = *reinterpret_cast<const float4*>(&wq_s[hh*256 + c]);
    float p = kv.x*w.x + kv.y*w.y + kv.z*w.z + kv.w*w.w;
    p = wave_sum(p);
    if(lane==0) scores[(size_t)(b*8+hh)*N_ + n] = valid ? (p + qconst[b*8+hh]) : -1e9f;
  }
}

// ---------------- softmax stage A: per-chunk max + local sum-exp ----------------
__global__ __launch_bounds__(256) void k_softA(
    const float* __restrict__ scores, float* __restrict__ pm,
    float* __restrict__ ps){
  __shared__ float red[4];
  int bh = blockIdx.x / 10;
  int c0 = (blockIdx.x % 10) * 1000;
  int tid = threadIdx.x;
  float m = -3e38f;
  for(int n=tid; n<1000; n+=256) m = fmaxf(m, scores[(size_t)bh*N_ + c0 + n]);
  #pragma unroll
  for(int o=32;o>0;o>>=1) m = fmaxf(m, __shfl_xor(m,o));
  if((tid&63)==0) red[tid>>6] = m;
  __syncthreads();
  m = fmaxf(fmaxf(red[0],red[1]), fmaxf(red[2],red[3]));
  __syncthreads();
  float s = 0.f;
  for(int n=tid; n<1000; n+=256) s += __expf(scores[(size_t)bh*N_ + c0 + n] - m);
  s = block_sum(s, red);
  if(tid==0){ pm[blockIdx.x] = m; ps[blockIdx.x] = s; }
}

// ---- kbar: 1000 blocks, 40 rows each; merges chunk stats inline, exp on the fly ----
__global__ __launch_bounds__(256) void k_kbar(
    const unsigned short* __restrict__ kbuf, const float* __restrict__ scores,
    const float* __restrict__ pm, const float* __restrict__ ps,
    float* __restrict__ kbar){
  __shared__ float p_s[8][40];
  __shared__ float mg_s[8], inv_s[8];
  int b = blockIdx.x / 250;
  int n0 = (blockIdx.x % 250) * 40;
  if(threadIdx.x < 8){
    int bh = b*8 + threadIdx.x;
    float m = -3e38f;
    #pragma unroll
    for(int c=0;c<10;c++) m = fmaxf(m, pm[bh*10+c]);
    float s = 0.f;
    #pragma unroll
    for(int c=0;c<10;c++) s += ps[bh*10+c]*__expf(pm[bh*10+c]-m);
    mg_s[threadIdx.x] = m;
    inv_s[threadIdx.x] = 1.f/s;
  }
  __syncthreads();
  for(int i=threadIdx.x; i<8*40; i+=256){
    int hh = i/40, nn = i - hh*40;
    p_s[hh][nn] = __expf(scores[(size_t)(b*8+hh)*N_ + n0 + nn] - mg_s[hh]);
  }
  __syncthreads();
  int c = threadIdx.x;
  float acc[8] = {0.f,0.f,0.f,0.f,0.f,0.f,0.f,0.f};
  for(int nn=0; nn<40; ++nn){
    float kv = bf2f(kbuf[(size_t)(b*N_ + n0 + nn)*D_ + c]);
    #pragma unroll
    for(int hh=0;hh<8;hh++) acc[hh] += p_s[hh][nn]*kv;
  }
  #pragma unroll
  for(int hh=0;hh<8;hh++)
    atomicAdd(&kbar[(b*8+hh)*D_ + c], acc[hh]*inv_s[hh]);
}

// ---------------- final ----------------
__global__ __launch_bounds__(256) void k_final(
    const float* __restrict__ kbar, const float* __restrict__ Wv,
    const float* __restrict__ bv, const float* __restrict__ Wo,
    const float* __restrict__ bo, const float* __restrict__ q_in,
    const float* __restrict__ lnf_s, const float* __restrict__ lnf_b,
    float* __restrict__ out){
  __shared__ float kb_s[2048];
  __shared__ float o_s[256];
  __shared__ float red[4];
  int b = blockIdx.x, c = threadIdx.x;
  for(int i=c; i<2048; i+=256) kb_s[i] = kbar[b*2048 + i];
  __syncthreads();
  int hh = c >> 5;
  float o = bv[c];
  for(int d=0; d<256; d++) o += kb_s[hh*256 + d]*Wv[(size_t)d*D_ + c];
  o_s[c] = o;
  __syncthreads();
  float y = bo[c] + q_in[b*D_ + c];
  for(int d=0; d<256; d++) y += o_s[d]*Wo[(size_t)d*D_ + c];
  float s1 = block_sum(y, red);
  float mean = s1*(1.f/256.f);
  float dd = y - mean;
  float s2 = block_sum(dd*dd, red);
  float v = dd * rsqrtf(s2*(1.f/256.f) + 1e-6f) * lnf_s[c] + lnf_b[c];
  out[b*D_ + c] = fmaxf(v, 0.f);
}

extern "C" void kernel_launch(void* const* d_in, const int* in_sizes, int n_in,
                              void* d_out, int out_size, void* d_ws, size_t ws_size,
                              hipStream_t stream){
  const float* nf    = (const float*)d_in[0];
  const float* ef    = (const float*)d_in[1];
  const float* gf    = (const float*)d_in[2];
  const int*   el    = (const int*)d_in[3];
  const int*   emask = (const int*)d_in[4];
  const int*   nmask = (const int*)d_in[5];
  const int*   agent = (const int*)d_in[6];
  const float* W_node = (const float*)d_in[7];
  const float* b_node = (const float*)d_in[8];
  const float* W_edge = (const float*)d_in[9];
  const float* b_edge = (const float*)d_in[10];
  const float* ln_e_s = (const float*)d_in[11];
  const float* ln_e_b = (const float*)d_in[12];
  const float* gcn_W  = (const float*)d_in[13];
  const float* gcn_b  = (const float*)d_in[14];
  const float* ln_s   = (const float*)d_in[15];
  const float* ln_b   = (const float*)d_in[16];
  const float* lnq_s  = (const float*)d_in[17];
  const float* lnq_b  = (const float*)d_in[18];
  const float* lnk_s  = (const float*)d_in[19];
  const float* lnk_b  = (const float*)d_in[20];
  const float* Wq = (const float*)d_in[21];
  const float* bq = (const float*)d_in[22];
  const float* Wk = (const float*)d_in[23];
  const float* bk = (const float*)d_in[24];
  const float* Wv = (const float*)d_in[25];
  const float* bv = (const float*)d_in[26];
  const float* Wo = (const float*)d_in[27];
  const float* bo = (const float*)d_in[28];
  const float* lnf_s = (const float*)d_in[29];
  const float* lnf_b = (const float*)d_in[30];
  float* out = (float*)d_out;

  const size_t ND = (size_t)BN_*D_;
  char* w = (char*)d_ws;
  float* h_buf = (float*)w;                   w += ND*4;
  unsigned short* hb16 = (unsigned short*)w;  w += (size_t)MPAD*D_*2;
  unsigned short* hn_bf = (unsigned short*)w; w += (size_t)MPAD*D_*2;
  unsigned short* A_bf = (unsigned short*)w;  w += (size_t)MPAD*512*2;
  unsigned short* Wt = (unsigned short*)w;    w += (size_t)3*256*512*2;
  float* scores = (float*)w;                  w += (size_t)B_*8*N_*4;
  float* q_in = (float*)w;                    w += B_*D_*4;
  float* Wq_eff = (float*)w;                  w += B_*8*D_*4;
  float* qconst = (float*)w;                  w += B_*8*4;
  float* pm = (float*)w;                      w += 320*4;
  float* ps = (float*)w;                      w += 320*4;
  float* kbar = (float*)w;                    w += B_*8*D_*4;
  float* prep = (float*)w;                    w += 512*4;
  int* counts = (int*)w;                      w += BN_*4;
  int* cursor = (int*)w;                      w += BN_*4;
  int* offsets = (int*)w;                     w += (BN_+1)*4;
  int* bsum = (int*)w;                        w += SCAN_NBLK*4;
  int* boff = (int*)w;                        w += SCAN_NBLK*4;
  int* s_send = (int*)w;                      w += (size_t)B_*E_*4;
  float* ef_slot = (float*)w;                 w += (size_t)B_*E_*16*4;
  float* stats = (float*)w;                   w += (size_t)B_*E_*2*4;
  unsigned short* kbuf = (unsigned short*)A_bf; // A dead after layers; reuse

  hipMemsetAsync(counts, 0, sizeof(int)*(size_t)2*BN_, stream);   // counts+cursor
  hipMemsetAsync(kbar, 0, sizeof(float)*(size_t)B_*8*D_, stream);

  k_node_in<<<BN_/16, 256, 0, stream>>>(nf, gf, W_node, b_node, ln_s, ln_b, hn_bf);
  k_hist<<<B_*E_/256, 256, 0, stream>>>(el, emask, counts);
  k_scanA<<<SCAN_NBLK, 256, 0, stream>>>(counts, bsum);
  k_scanB_eprep<<<2, 256, 0, stream>>>(bsum, boff, W_edge, b_edge, prep);
  k_scanC<<<SCAN_NBLK, 256, 0, stream>>>(counts, boff, offsets);
  k_fill<<<B_*E_/256, 256, 0, stream>>>(el, emask, ef, prep, offsets, cursor,
                                        s_send, ef_slot, stats);
  k_wt<<<384, 256, 0, stream>>>(gcn_W, Wt);
  k_se_wave<<<BN_/4, 256, 0, stream>>>(ef_slot, stats, W_edge, b_edge,
                                       ln_e_s, ln_e_b, offsets, A_bf);

  for(int i=0;i<3;i++){
    k_agg<<<BN_/4, 256, 0, stream>>>(hn_bf, offsets, s_send, A_bf);
    if(i < 2){
      k_gemm_mfma<<<(MPAD/128)*2, 256, 0, stream>>>(A_bf, Wt + (size_t)i*256*512,
                                                    gcn_b + i*D_, counts, hn_bf,
                                                    h_buf, nullptr);
      k_ln_relu<<<BN_/4, 256, 0, stream>>>(h_buf, ln_s + (i+1)*D_, ln_b + (i+1)*D_, hn_bf);
    } else {
      k_gemm_mfma<<<(MPAD/128)*2, 256, 0, stream>>>(A_bf, Wt + (size_t)i*256*512,
                                                    gcn_b + i*D_, counts, hn_bf,
                                                    nullptr, hb16);
    }
  }

  k_qprep<<<B_, 256, 0, stream>>>(hb16, agent, lnq_s, lnq_b, Wq, bq, Wk, bk,
                                  q_in, Wq_eff, qconst);
  k_scores<<<BN_/4, 256, 0, stream>>>(hb16, lnk_s, lnk_b, Wq_eff, qconst, nmask,
                                      kbuf, scores);
  k_softA<<<320, 256, 0, stream>>>(scores, pm, ps);
  k_kbar<<<B_*250, 256, 0, stream>>>(kbuf, scores, pm, ps, kbar);
  k_final<<<B_, 256, 0, stream>>>(kbar, Wv, bv, Wo, bo, q_in, lnf_s, lnf_b, out);
}

// Round 14
// 472.205 us; speedup vs baseline: 1.1315x; 1.0249x over previous
//
#include <hip/hip_runtime.h>
#include <hip/hip_bf16.h>

#define B_ 4
#define N_ 10000
#define E_ 80000
#define D_ 256
#define BN_ (B_*N_)
#define MPAD 40064
#define SCAN_NBLK ((BN_ + 255) / 256)

typedef __attribute__((ext_vector_type(8))) short short8;
typedef __attribute__((ext_vector_type(4))) float f32x4;
typedef __attribute__((ext_vector_type(4))) unsigned short u16x4;

static __device__ __forceinline__ float wave_sum(float v){
  #pragma unroll
  for(int o=32;o>0;o>>=1) v += __shfl_xor(v, o);
  return v;
}

static __device__ __forceinline__ float block_sum(float v, float* red){
  v = wave_sum(v);
  int w = threadIdx.x >> 6;
  if((threadIdx.x & 63) == 0) red[w] = v;
  __syncthreads();
  float r = (red[0] + red[1]) + (red[2] + red[3]);
  __syncthreads();
  return r;
}

static __device__ __forceinline__ unsigned short f2bf(float f){
  unsigned u = __float_as_uint(f);
  return (unsigned short)((u + 0x7fffu + ((u>>16)&1u)) >> 16);
}
static __device__ __forceinline__ float bf2f(unsigned short b){
  return __uint_as_float(((unsigned)b) << 16);
}

// ------- node input projection + LN0 + relu -> hn0 (bf16) -------
__global__ __launch_bounds__(256) void k_node_in(
    const float* __restrict__ nf, const float* __restrict__ gf,
    const float* __restrict__ W, const float* __restrict__ bias,
    const float* __restrict__ lns, const float* __restrict__ lnb,
    unsigned short* __restrict__ hnbf){
  __shared__ float in_s[16][96];
  __shared__ float h_s[16][256];
  int base = blockIdx.x * 16;
  int tid = threadIdx.x;
  for(int idx = tid; idx < 16*96; idx += 256){
    int i = idx / 96, k = idx - i*96;
    int row = base + i;
    int b = row / N_;
    float v = (k < 64) ? nf[(size_t)row*64 + k] : gf[b*32 + (k-64)];
    in_s[i][k] = v;
  }
  __syncthreads();
  int c = tid;
  float acc[16];
  #pragma unroll
  for(int i=0;i<16;i++) acc[i]=0.f;
  for(int k=0;k<96;k+=4){
    float w0 = W[(k+0)*D_+c], w1 = W[(k+1)*D_+c];
    float w2 = W[(k+2)*D_+c], w3 = W[(k+3)*D_+c];
    #pragma unroll
    for(int i=0;i<16;i++){
      float4 a = *reinterpret_cast<const float4*>(&in_s[i][k]);
      acc[i] += a.x*w0 + a.y*w1 + a.z*w2 + a.w*w3;
    }
  }
  float bc = bias[c];
  #pragma unroll
  for(int i=0;i<16;i++) h_s[i][c] = acc[i] + bc;
  __syncthreads();
  int wv = tid>>6, lane = tid&63;
  float4 s4 = *reinterpret_cast<const float4*>(&lns[lane*4]);
  float4 b4 = *reinterpret_cast<const float4*>(&lnb[lane*4]);
  #pragma unroll
  for(int rr=0; rr<4; ++rr){
    int i = wv*4 + rr;
    float4 x = *reinterpret_cast<const float4*>(&h_s[i][lane*4]);
    float sum = x.x+x.y+x.z+x.w;
    float sq = x.x*x.x+x.y*x.y+x.z*x.z+x.w*x.w;
    #pragma unroll
    for(int o=32;o>0;o>>=1){ sum += __shfl_xor(sum,o); sq += __shfl_xor(sq,o); }
    float mean = sum*(1.f/256.f);
    float var = sq*(1.f/256.f) - mean*mean;
    float rs = rsqrtf(var + 1e-6f);
    u16x4 o;
    o.x = f2bf(fmaxf((x.x-mean)*rs*s4.x + b4.x, 0.f));
    o.y = f2bf(fmaxf((x.y-mean)*rs*s4.y + b4.y, 0.f));
    o.z = f2bf(fmaxf((x.z-mean)*rs*s4.z + b4.z, 0.f));
    o.w = f2bf(fmaxf((x.w-mean)*rs*s4.w + b4.w, 0.f));
    *reinterpret_cast<u16x4*>(&hnbf[(size_t)(base+i)*D_ + lane*4]) = o;
  }
}

// ---------------- CSR build ----------------
__global__ __launch_bounds__(256) void k_hist(
    const int* __restrict__ el, const int* __restrict__ emask,
    int* __restrict__ counts){
  int e = blockIdx.x*256 + threadIdx.x;
  if(e >= B_*E_) return;
  if(emask[e]){
    int b = e / E_;
    int r = el[(size_t)e*2 + 1];
    atomicAdd(&counts[b*N_ + r], 1);
  }
}

// ---- multi-block exclusive scan of counts[BN_] -> offsets[BN_+1] ----
__global__ __launch_bounds__(256) void k_scanA(
    const int* __restrict__ counts, int* __restrict__ bsum){
  __shared__ int red[4];
  int idx = blockIdx.x*256 + threadIdx.x;
  int x = (idx < BN_) ? counts[idx] : 0;
  int lane = threadIdx.x & 63, w = threadIdx.x >> 6;
  int s = x;
  #pragma unroll
  for(int o=32;o>0;o>>=1) s += __shfl_xor(s, o);
  if(lane == 0) red[w] = s;
  __syncthreads();
  if(threadIdx.x == 0) bsum[blockIdx.x] = red[0]+red[1]+red[2]+red[3];
}

// block 0: scan of block sums; block 1: edge-LN stats prep (290 floats)
__global__ __launch_bounds__(256) void k_scanB_eprep(
    const int* __restrict__ bsum, int* __restrict__ boff,
    const float* __restrict__ W, const float* __restrict__ be,
    float* __restrict__ prep){
  if(blockIdx.x == 0){
    __shared__ int ws[4];
    int t = threadIdx.x;
    int x = (t < SCAN_NBLK) ? bsum[t] : 0;
    int lane = t & 63, w = t >> 6;
    int incl = x;
    #pragma unroll
    for(int o=1;o<64;o<<=1){ int v=__shfl_up(incl,o); if(lane>=o) incl+=v; }
    if(lane == 63) ws[w] = incl;
    __syncthreads();
    int pre = 0;
    for(int i=0;i<w;i++) pre += ws[i];
    if(t < SCAN_NBLK) boff[t] = pre + incl - x;
  } else {
    int t = threadIdx.x;
    int i = t >> 4, j = t & 15;
    float m = 0.f;
    for(int c=0;c<256;c++) m += W[i*256+c]*W[j*256+c];
    prep[t] = m;
    if(t < 16){
      float v=0.f, wb=0.f;
      for(int c=0;c<256;c++){ v += W[t*256+c]*be[c]; wb += W[t*256+c]; }
      prep[256+t] = v;
      prep[272+t] = wb*(1.f/256.f);
    }
    if(t == 0){
      float bb=0.f, ss=0.f;
      for(int c=0;c<256;c++){ bb += be[c]; ss += be[c]*be[c]; }
      prep[288] = bb*(1.f/256.f);
      prep[289] = ss;
    }
  }
}

__global__ __launch_bounds__(256) void k_scanC(
    const int* __restrict__ counts, const int* __restrict__ boff,
    int* __restrict__ offsets){
  __shared__ int ws[4];
  int idx = blockIdx.x*256 + threadIdx.x;
  int x = (idx < BN_) ? counts[idx] : 0;
  int lane = threadIdx.x & 63, w = threadIdx.x >> 6;
  int incl = x;
  #pragma unroll
  for(int o=1;o<64;o<<=1){ int v=__shfl_up(incl,o); if(lane>=o) incl+=v; }
  if(lane == 63) ws[w] = incl;
  __syncthreads();
  int pre = boff[blockIdx.x];
  for(int i=0;i<w;i++) pre += ws[i];
  int excl = pre + incl - x;
  if(idx < BN_) offsets[idx] = excl;
  if(idx == BN_-1) offsets[BN_] = excl + x;
}

// fill CSR; pre-gather edge features into slot order; compute per-edge LN stats.
__global__ __launch_bounds__(256) void k_fill(
    const int* __restrict__ el, const int* __restrict__ emask,
    const float* __restrict__ ef, const float* __restrict__ prep,
    const int* __restrict__ offsets, int* __restrict__ cursor,
    int* __restrict__ s_send, float* __restrict__ ef_slot,
    float* __restrict__ stats){
  __shared__ float M_s[290];
  for(int i=threadIdx.x; i<290; i+=256) M_s[i] = prep[i];
  __syncthreads();
  int e = blockIdx.x*256 + threadIdx.x;
  if(e >= B_*E_) return;
  if(!emask[e]) return;
  int b = e / E_;
  int s = el[(size_t)e*2], r = el[(size_t)e*2 + 1];
  int bn = b*N_ + r;
  int pos = offsets[bn] + atomicAdd(&cursor[bn], 1);
  s_send[pos] = b*N_ + s;
  const float4* src = reinterpret_cast<const float4*>(ef + (size_t)e*16);
  float4 f0=src[0], f1=src[1], f2=src[2], f3=src[3];
  float4* dst = reinterpret_cast<float4*>(ef_slot + (size_t)pos*16);
  dst[0]=f0; dst[1]=f1; dst[2]=f2; dst[3]=f3;
  float f[16] = {f0.x,f0.y,f0.z,f0.w, f1.x,f1.y,f1.z,f1.w,
                 f2.x,f2.y,f2.z,f2.w, f3.x,f3.y,f3.z,f3.w};
  float mean = M_s[288];
  #pragma unroll
  for(int k=0;k<16;k++) mean += f[k]*M_s[272+k];
  float q = M_s[289];
  #pragma unroll
  for(int i=0;i<16;i++){
    float pi = 2.f*M_s[256+i];
    #pragma unroll
    for(int j=0;j<16;j++) pi += M_s[i*16+j]*f[j];
    q += f[i]*pi;
  }
  float var = q*(1.f/256.f) - mean*mean;
  float rstd = rsqrtf(var + 1e-6f);
  stats[(size_t)pos*2]   = mean;
  stats[(size_t)pos*2+1] = rstd;
}

// ---------------- weights: transpose + bf16: Wt[l][n][k] ----------------
__global__ __launch_bounds__(256) void k_wt(
    const float* __restrict__ gcnW, unsigned short* __restrict__ Wt){
  __shared__ float sm[32][33];
  int bid = blockIdx.x;
  int l = bid >> 7;
  int t = bid & 127;
  int k0 = (t >> 3)*32, n0 = (t & 7)*32;
  int r = threadIdx.x >> 3;
  int c4 = (threadIdx.x & 7)*4;
  const float* src = gcnW + (size_t)l*512*256;
  float4 v = *reinterpret_cast<const float4*>(&src[(size_t)(k0+r)*256 + n0 + c4]);
  sm[r][c4+0]=v.x; sm[r][c4+1]=v.y; sm[r][c4+2]=v.z; sm[r][c4+3]=v.w;
  __syncthreads();
  u16x4 o;
  o.x = f2bf(sm[c4+0][r]); o.y = f2bf(sm[c4+1][r]);
  o.z = f2bf(sm[c4+2][r]); o.w = f2bf(sm[c4+3][r]);
  *reinterpret_cast<u16x4*>(&Wt[(size_t)l*256*512 + (size_t)(n0+r)*512 + k0 + c4]) = o;
}

// ------- edge proj + LN(precomputed stats) + relu, CSR-gathered; no shuffles -------
#define PROJ(F0,F1,F2,F3,COMP) (be4.COMP \
  + F0.x*w[0].COMP + F0.y*w[1].COMP + F0.z*w[2].COMP + F0.w*w[3].COMP \
  + F1.x*w[4].COMP + F1.y*w[5].COMP + F1.z*w[6].COMP + F1.w*w[7].COMP \
  + F2.x*w[8].COMP + F2.y*w[9].COMP + F2.z*w[10].COMP + F2.w*w[11].COMP \
  + F3.x*w[12].COMP + F3.y*w[13].COMP + F3.z*w[14].COMP + F3.w*w[15].COMP)

__global__ __launch_bounds__(256) void k_se_wave(
    const float* __restrict__ ef_slot, const float* __restrict__ stats,
    const float* __restrict__ W, const float* __restrict__ be,
    const float* __restrict__ lns, const float* __restrict__ lnb,
    const int* __restrict__ offsets, unsigned short* __restrict__ Abf){
  int bn = blockIdx.x*4 + (threadIdx.x>>6);
  int lane = threadIdx.x & 63;
  int c = lane*4;
  float4 w[16];
  #pragma unroll
  for(int k=0;k<16;k++) w[k] = *reinterpret_cast<const float4*>(&W[k*D_ + c]);
  float4 be4 = *reinterpret_cast<const float4*>(&be[c]);
  float4 s4  = *reinterpret_cast<const float4*>(&lns[c]);
  float4 b4  = *reinterpret_cast<const float4*>(&lnb[c]);
  int beg = __builtin_amdgcn_readfirstlane(offsets[bn]);
  int end = __builtin_amdgcn_readfirstlane(offsets[bn+1]);
  float a0=0.f,a1=0.f,a2=0.f,a3=0.f;
  int slot = beg;
  for(; slot+2 <= end; slot += 2){
    const float4* e0 = reinterpret_cast<const float4*>(ef_slot + (size_t)slot*16);
    const float4* e1 = reinterpret_cast<const float4*>(ef_slot + (size_t)(slot+1)*16);
    float2 st0 = *reinterpret_cast<const float2*>(stats + (size_t)slot*2);
    float2 st1 = *reinterpret_cast<const float2*>(stats + (size_t)(slot+1)*2);
    float4 f0=e0[0], f1=e0[1], f2=e0[2], f3=e0[3];
    float4 g0=e1[0], g1=e1[1], g2=e1[2], g3=e1[3];
    float t0=PROJ(f0,f1,f2,f3,x), t1=PROJ(f0,f1,f2,f3,y);
    float t2=PROJ(f0,f1,f2,f3,z), t3=PROJ(f0,f1,f2,f3,w);
    float u0=PROJ(g0,g1,g2,g3,x), u1=PROJ(g0,g1,g2,g3,y);
    float u2=PROJ(g0,g1,g2,g3,z), u3=PROJ(g0,g1,g2,g3,w);
    float m0=st0.x, r0=st0.y, m1=st1.x, r1=st1.y;
    a0 += fmaxf((t0-m0)*r0*s4.x + b4.x, 0.f) + fmaxf((u0-m1)*r1*s4.x + b4.x, 0.f);
    a1 += fmaxf((t1-m0)*r0*s4.y + b4.y, 0.f) + fmaxf((u1-m1)*r1*s4.y + b4.y, 0.f);
    a2 += fmaxf((t2-m0)*r0*s4.z + b4.z, 0.f) + fmaxf((u2-m1)*r1*s4.z + b4.z, 0.f);
    a3 += fmaxf((t3-m0)*r0*s4.w + b4.w, 0.f) + fmaxf((u3-m1)*r1*s4.w + b4.w, 0.f);
  }
  if(slot < end){
    const float4* e0 = reinterpret_cast<const float4*>(ef_slot + (size_t)slot*16);
    float2 st0 = *reinterpret_cast<const float2*>(stats + (size_t)slot*2);
    float4 f0=e0[0], f1=e0[1], f2=e0[2], f3=e0[3];
    float t0=PROJ(f0,f1,f2,f3,x), t1=PROJ(f0,f1,f2,f3,y);
    float t2=PROJ(f0,f1,f2,f3,z), t3=PROJ(f0,f1,f2,f3,w);
    float m0=st0.x, r0=st0.y;
    a0 += fmaxf((t0-m0)*r0*s4.x + b4.x, 0.f);
    a1 += fmaxf((t1-m0)*r0*s4.y + b4.y, 0.f);
    a2 += fmaxf((t2-m0)*r0*s4.z + b4.z, 0.f);
    a3 += fmaxf((t3-m0)*r0*s4.w + b4.w, 0.f);
  }
  u16x4 o; o.x=f2bf(a0); o.y=f2bf(a1); o.z=f2bf(a2); o.w=f2bf(a3);
  *reinterpret_cast<u16x4*>(Abf + (size_t)bn*512 + 256 + c) = o;
}

// ---------------- LN + relu (bf16 in) -> hn (bf16) ----------------
__global__ __launch_bounds__(256) void k_ln_relu(
    const unsigned short* __restrict__ h16, const float* __restrict__ s,
    const float* __restrict__ b, unsigned short* __restrict__ hnbf){
  int row = blockIdx.x*4 + (threadIdx.x>>6);
  int lane = threadIdx.x & 63;
  int c = lane*4;
  u16x4 xv = *reinterpret_cast<const u16x4*>(h16 + (size_t)row*D_ + c);
  float4 x; x.x=bf2f(xv.x); x.y=bf2f(xv.y); x.z=bf2f(xv.z); x.w=bf2f(xv.w);
  float sum = x.x+x.y+x.z+x.w;
  float sq = x.x*x.x+x.y*x.y+x.z*x.z+x.w*x.w;
  #pragma unroll
  for(int o=32;o>0;o>>=1){ sum += __shfl_xor(sum,o); sq += __shfl_xor(sq,o); }
  float mean = sum*(1.f/256.f);
  float var = sq*(1.f/256.f) - mean*mean;
  float rs = rsqrtf(var + 1e-6f);
  float4 s4 = *reinterpret_cast<const float4*>(&s[c]);
  float4 b4 = *reinterpret_cast<const float4*>(&b[c]);
  u16x4 o;
  o.x = f2bf(fmaxf((x.x-mean)*rs*s4.x + b4.x, 0.f));
  o.y = f2bf(fmaxf((x.y-mean)*rs*s4.y + b4.y, 0.f));
  o.z = f2bf(fmaxf((x.z-mean)*rs*s4.z + b4.z, 0.f));
  o.w = f2bf(fmaxf((x.w-mean)*rs*s4.w + b4.w, 0.f));
  *reinterpret_cast<u16x4*>(&hnbf[(size_t)row*D_ + c]) = o;
}

// ---------------- gather-sum senders -> A[:,0:256] (bf16), 4-deep ----------------
__global__ __launch_bounds__(256) void k_agg(
    const unsigned short* __restrict__ hnbf, const int* __restrict__ offsets,
    const int* __restrict__ s_send, unsigned short* __restrict__ Abf){
  int bn = blockIdx.x*4 + (threadIdx.x>>6);
  int lane = threadIdx.x & 63;
  int beg = __builtin_amdgcn_readfirstlane(offsets[bn]);
  int end = __builtin_amdgcn_readfirstlane(offsets[bn+1]);
  float a0=0.f,a1=0.f,a2=0.f,a3=0.f;
  int slot = beg;
  for(; slot+4 <= end; slot += 4){
    int sr0 = s_send[slot],   sr1 = s_send[slot+1];
    int sr2 = s_send[slot+2], sr3 = s_send[slot+3];
    u16x4 v0 = *reinterpret_cast<const u16x4*>(hnbf + (size_t)sr0*D_ + lane*4);
    u16x4 v1 = *reinterpret_cast<const u16x4*>(hnbf + (size_t)sr1*D_ + lane*4);
    u16x4 v2 = *reinterpret_cast<const u16x4*>(hnbf + (size_t)sr2*D_ + lane*4);
    u16x4 v3 = *reinterpret_cast<const u16x4*>(hnbf + (size_t)sr3*D_ + lane*4);
    a0 += bf2f(v0.x)+bf2f(v1.x)+bf2f(v2.x)+bf2f(v3.x);
    a1 += bf2f(v0.y)+bf2f(v1.y)+bf2f(v2.y)+bf2f(v3.y);
    a2 += bf2f(v0.z)+bf2f(v1.z)+bf2f(v2.z)+bf2f(v3.z);
    a3 += bf2f(v0.w)+bf2f(v1.w)+bf2f(v2.w)+bf2f(v3.w);
  }
  for(; slot < end; ++slot){
    int sr = s_send[slot];
    u16x4 v = *reinterpret_cast<const u16x4*>(hnbf + (size_t)sr*D_ + lane*4);
    a0 += bf2f(v.x); a1 += bf2f(v.y); a2 += bf2f(v.z); a3 += bf2f(v.w);
  }
  u16x4 o; o.x=f2bf(a0); o.y=f2bf(a1); o.z=f2bf(a2); o.w=f2bf(a3);
  *reinterpret_cast<u16x4*>(Abf + (size_t)bn*512 + lane*4) = o;
}

// ------- MFMA GEMM: h16 = bf16( hn + (A@Wt^T + cnt*bias)/deg ) -------
__global__ __launch_bounds__(256) void k_gemm_mfma(
    const unsigned short* __restrict__ Abf,
    const unsigned short* __restrict__ Wt,
    const float* __restrict__ bias,
    const int* __restrict__ counts,
    const unsigned short* __restrict__ hnbf,
    unsigned short* __restrict__ hout_bf){
  __shared__ unsigned short A_s[128*32];
  __shared__ unsigned short B_s[128*32];
  int bid = blockIdx.x;
  int row0 = (bid>>1)*128;
  int col0 = (bid&1)*128;
  int tid = threadIdx.x;
  int lane = tid & 63;
  int wid = tid >> 6;
  int wr = wid >> 1, wc = wid & 1;
  f32x4 acc[4][4];
  #pragma unroll
  for(int m=0;m<4;m++)
    #pragma unroll
    for(int n=0;n<4;n++) acc[m][n] = (f32x4){0.f,0.f,0.f,0.f};

  int sr = tid >> 1;
  int sc0 = (tid & 1)*2;
  const unsigned short* agp = Abf + (size_t)(row0+sr)*512;
  const unsigned short* bgp = Wt  + (size_t)(col0+sr)*512;
  unsigned swA0 = (unsigned)(sr*64 + (((sc0  ) ^ (sr&3))*16));
  unsigned swA1 = (unsigned)(sr*64 + (((sc0+1) ^ (sr&3))*16));
  int frow = lane & 15;
  int fsw = (lane >> 4) ^ (lane & 3);

  for(int k0=0; k0<512; k0+=32){
    short8 a0 = *reinterpret_cast<const short8*>(agp + k0 + sc0*8);
    short8 a1 = *reinterpret_cast<const short8*>(agp + k0 + sc0*8 + 8);
    short8 b0 = *reinterpret_cast<const short8*>(bgp + k0 + sc0*8);
    short8 b1 = *reinterpret_cast<const short8*>(bgp + k0 + sc0*8 + 8);
    __syncthreads();
    *reinterpret_cast<short8*>((char*)A_s + swA0) = a0;
    *reinterpret_cast<short8*>((char*)A_s + swA1) = a1;
    *reinterpret_cast<short8*>((char*)B_s + swA0) = b0;
    *reinterpret_cast<short8*>((char*)B_s + swA1) = b1;
    __syncthreads();
    short8 af[4], bfr[4];
    #pragma unroll
    for(int m=0;m<4;m++){
      int r = wr*64 + m*16 + frow;
      af[m] = *reinterpret_cast<const short8*>((const char*)A_s + r*64 + fsw*16);
    }
    #pragma unroll
    for(int n=0;n<4;n++){
      int r = wc*64 + n*16 + frow;
      bfr[n] = *reinterpret_cast<const short8*>((const char*)B_s + r*64 + fsw*16);
    }
    #pragma unroll
    for(int m=0;m<4;m++)
      #pragma unroll
      for(int n=0;n<4;n++)
        acc[m][n] = __builtin_amdgcn_mfma_f32_16x16x32_bf16(af[m], bfr[n], acc[m][n], 0, 0, 0);
  }
  #pragma unroll
  for(int m=0;m<4;m++){
    #pragma unroll
    for(int n=0;n<4;n++){
      int col = col0 + wc*64 + n*16 + (lane&15);
      int rbase = row0 + wr*64 + m*16 + (lane>>4)*4;
      float bcol = bias[col];
      #pragma unroll
      for(int j=0;j<4;j++){
        int r = rbase + j;
        if(r < BN_){
          float cnt = (float)counts[r];
          float inv = 1.f / fmaxf(cnt, 1.f);
          float v = bf2f(hnbf[(size_t)r*D_ + col]) + (acc[m][n][j] + cnt*bcol)*inv;
          hout_bf[(size_t)r*D_ + col] = f2bf(v);
        }
      }
    }
  }
}

// ---------------- attention prep (h in bf16) ----------------
__global__ __launch_bounds__(256) void k_qprep(
    const unsigned short* __restrict__ hb, const int* __restrict__ agent,
    const float* __restrict__ lnq_s, const float* __restrict__ lnq_b,
    const float* __restrict__ Wq, const float* __restrict__ bq,
    const float* __restrict__ Wk, const float* __restrict__ bk,
    float* __restrict__ q_in, float* __restrict__ Wq_eff,
    float* __restrict__ qconst){
  __shared__ float q_s[256];
  __shared__ float Q_s[256];
  __shared__ float red[4];
  int b = blockIdx.x, c = threadIdx.x;
  size_t row = (size_t)(b*N_ + agent[b]);
  float x = bf2f(hb[row*D_ + c]);
  q_in[b*D_ + c] = x;
  float s1 = block_sum(x, red);
  float mean = s1*(1.f/256.f);
  float d = x - mean;
  float s2 = block_sum(d*d, red);
  float q = d * rsqrtf(s2*(1.f/256.f) + 1e-6f) * lnq_s[c] + lnq_b[c];
  q_s[c] = q;
  __syncthreads();
  float acc = bq[c];
  for(int k=0;k<256;k++) acc += q_s[k]*Wq[k*D_ + c];
  Q_s[c] = acc;
  __syncthreads();
  const float scale = 0.17677669529663687f; // 1/sqrt(32)
  for(int idx=c; idx<2048; idx+=256){
    int hh = idx >> 8, dd = idx & 255;
    const float4* wk4 = reinterpret_cast<const float4*>(&Wk[(size_t)dd*D_ + hh*32]);
    const float4* q4  = reinterpret_cast<const float4*>(&Q_s[hh*32]);
    float t = 0.f;
    #pragma unroll
    for(int k4=0;k4<8;k4++){
      float4 w = wk4[k4]; float4 qq = q4[k4];
      t += w.x*qq.x + w.y*qq.y + w.z*qq.z + w.w*qq.w;
    }
    Wq_eff[b*2048 + hh*256 + dd] = t*scale;
  }
  if(c < 8){
    float t = 0.f;
    for(int dh=0; dh<32; dh++) t += Q_s[c*32+dh]*bk[c*32+dh];
    qconst[b*8 + c] = t*scale;
  }
}

// ------- LN(h bf16) row-stats + masked scores; K matrix never materialized -------
__global__ __launch_bounds__(256) void k_scores(
    const unsigned short* __restrict__ hb, const float* __restrict__ lnk_s,
    const float* __restrict__ lnk_b, const float* __restrict__ Wq_eff,
    const float* __restrict__ qconst, const int* __restrict__ nmask,
    float* __restrict__ rowstats, float* __restrict__ scores){
  __shared__ float wq_s[2048];
  int row0 = blockIdx.x * 4;
  int b = row0 / N_;
  for(int i=threadIdx.x; i<2048; i+=256) wq_s[i] = Wq_eff[b*2048 + i];
  __syncthreads();
  int wave = threadIdx.x >> 6, lane = threadIdx.x & 63;
  int row = row0 + wave;
  int n = row - b*N_;
  int c = lane*4;
  u16x4 xv = *reinterpret_cast<const u16x4*>(hb + (size_t)row*D_ + c);
  float4 x; x.x=bf2f(xv.x); x.y=bf2f(xv.y); x.z=bf2f(xv.z); x.w=bf2f(xv.w);
  float sum = x.x+x.y+x.z+x.w;
  float sq = x.x*x.x+x.y*x.y+x.z*x.z+x.w*x.w;
  #pragma unroll
  for(int o=32;o>0;o>>=1){ sum += __shfl_xor(sum,o); sq += __shfl_xor(sq,o); }
  float mean = sum*(1.f/256.f);
  float var = sq*(1.f/256.f) - mean*mean;
  float rs = rsqrtf(var + 1e-6f);
  if(lane == 0){
    float2 st; st.x = mean; st.y = rs;
    *reinterpret_cast<float2*>(&rowstats[(size_t)row*2]) = st;
  }
  float4 s4 = *reinterpret_cast<const float4*>(&lnk_s[c]);
  float4 b4 = *reinterpret_cast<const float4*>(&lnk_b[c]);
  float4 kv;
  kv.x = (x.x-mean)*rs*s4.x + b4.x;
  kv.y = (x.y-mean)*rs*s4.y + b4.y;
  kv.z = (x.z-mean)*rs*s4.z + b4.z;
  kv.w = (x.w-mean)*rs*s4.w + b4.w;
  bool valid = nmask[row] != 0;
  #pragma unroll
  for(int hh=0; hh<8; hh++){
    float4 w = *reinterpret_cast<const float4*>(&wq_s[hh*256 + c]);
    float p = kv.x*w.x + kv.y*w.y + kv.z*w.z + kv.w*w.w;
    p = wave_sum(p);
    if(lane==0) scores[(size_t)(b*8+hh)*N_ + n] = valid ? (p + qconst[b*8+hh]) : -1e9f;
  }
}

// ---------------- softmax stage A: per-chunk max + local sum-exp ----------------
__global__ __launch_bounds__(256) void k_softA(
    const float* __restrict__ scores, float* __restrict__ pm,
    float* __restrict__ ps){
  __shared__ float red[4];
  int bh = blockIdx.x / 10;
  int c0 = (blockIdx.x % 10) * 1000;
  int tid = threadIdx.x;
  float m = -3e38f;
  for(int n=tid; n<1000; n+=256) m = fmaxf(m, scores[(size_t)bh*N_ + c0 + n]);
  #pragma unroll
  for(int o=32;o>0;o>>=1) m = fmaxf(m, __shfl_xor(m,o));
  if((tid&63)==0) red[tid>>6] = m;
  __syncthreads();
  m = fmaxf(fmaxf(red[0],red[1]), fmaxf(red[2],red[3]));
  __syncthreads();
  float s = 0.f;
  for(int n=tid; n<1000; n+=256) s += __expf(scores[(size_t)bh*N_ + c0 + n] - m);
  s = block_sum(s, red);
  if(tid==0){ pm[blockIdx.x] = m; ps[blockIdx.x] = s; }
}

// ---- kbar: recompute K=LN(h) inline from h16 + rowstats; exp on the fly ----
__global__ __launch_bounds__(256) void k_kbar(
    const unsigned short* __restrict__ hb, const float* __restrict__ rowstats,
    const float* __restrict__ scores,
    const float* __restrict__ pm, const float* __restrict__ ps,
    const float* __restrict__ lnk_s, const float* __restrict__ lnk_b,
    float* __restrict__ kbar){
  __shared__ float p_s[8][40];
  __shared__ float mg_s[8], inv_s[8];
  int b = blockIdx.x / 250;
  int n0 = (blockIdx.x % 250) * 40;
  if(threadIdx.x < 8){
    int bh = b*8 + threadIdx.x;
    float m = -3e38f;
    #pragma unroll
    for(int c=0;c<10;c++) m = fmaxf(m, pm[bh*10+c]);
    float s = 0.f;
    #pragma unroll
    for(int c=0;c<10;c++) s += ps[bh*10+c]*__expf(pm[bh*10+c]-m);
    mg_s[threadIdx.x] = m;
    inv_s[threadIdx.x] = 1.f/s;
  }
  __syncthreads();
  for(int i=threadIdx.x; i<8*40; i+=256){
    int hh = i/40, nn = i - hh*40;
    p_s[hh][nn] = __expf(scores[(size_t)(b*8+hh)*N_ + n0 + nn] - mg_s[hh]);
  }
  __syncthreads();
  int c = threadIdx.x;
  float sc = lnk_s[c], bc = lnk_b[c];
  float acc[8] = {0.f,0.f,0.f,0.f,0.f,0.f,0.f,0.f};
  for(int nn=0; nn<40; ++nn){
    int row = b*N_ + n0 + nn;
    float2 st = *reinterpret_cast<const float2*>(rowstats + (size_t)row*2);
    float kv = (bf2f(hb[(size_t)row*D_ + c]) - st.x)*st.y*sc + bc;
    #pragma unroll
    for(int hh=0;hh<8;hh++) acc[hh] += p_s[hh][nn]*kv;
  }
  #pragma unroll
  for(int hh=0;hh<8;hh++)
    atomicAdd(&kbar[(b*8+hh)*D_ + c], acc[hh]*inv_s[hh]);
}

// ---------------- final ----------------
__global__ __launch_bounds__(256) void k_final(
    const float* __restrict__ kbar, const float* __restrict__ Wv,
    const float* __restrict__ bv, const float* __restrict__ Wo,
    const float* __restrict__ bo, const float* __restrict__ q_in,
    const float* __restrict__ lnf_s, const float* __restrict__ lnf_b,
    float* __restrict__ out){
  __shared__ float kb_s[2048];
  __shared__ float o_s[256];
  __shared__ float red[4];
  int b = blockIdx.x, c = threadIdx.x;
  for(int i=c; i<2048; i+=256) kb_s[i] = kbar[b*2048 + i];
  __syncthreads();
  int hh = c >> 5;
  float o = bv[c];
  for(int d=0; d<256; d++) o += kb_s[hh*256 + d]*Wv[(size_t)d*D_ + c];
  o_s[c] = o;
  __syncthreads();
  float y = bo[c] + q_in[b*D_ + c];
  for(int d=0; d<256; d++) y += o_s[d]*Wo[(size_t)d*D_ + c];
  float s1 = block_sum(y, red);
  float mean = s1*(1.f/256.f);
  float dd = y - mean;
  float s2 = block_sum(dd*dd, red);
  float v = dd * rsqrtf(s2*(1.f/256.f) + 1e-6f) * lnf_s[c] + lnf_b[c];
  out[b*D_ + c] = fmaxf(v, 0.f);
}

extern "C" void kernel_launch(void* const* d_in, const int* in_sizes, int n_in,
                              void* d_out, int out_size, void* d_ws, size_t ws_size,
                              hipStream_t stream){
  const float* nf    = (const float*)d_in[0];
  const float* ef    = (const float*)d_in[1];
  const float* gf    = (const float*)d_in[2];
  const int*   el    = (const int*)d_in[3];
  const int*   emask = (const int*)d_in[4];
  const int*   nmask = (const int*)d_in[5];
  const int*   agent = (const int*)d_in[6];
  const float* W_node = (const float*)d_in[7];
  const float* b_node = (const float*)d_in[8];
  const float* W_edge = (const float*)d_in[9];
  const float* b_edge = (const float*)d_in[10];
  const float* ln_e_s = (const float*)d_in[11];
  const float* ln_e_b = (const float*)d_in[12];
  const float* gcn_W  = (const float*)d_in[13];
  const float* gcn_b  = (const float*)d_in[14];
  const float* ln_s   = (const float*)d_in[15];
  const float* ln_b   = (const float*)d_in[16];
  const float* lnq_s  = (const float*)d_in[17];
  const float* lnq_b  = (const float*)d_in[18];
  const float* lnk_s  = (const float*)d_in[19];
  const float* lnk_b  = (const float*)d_in[20];
  const float* Wq = (const float*)d_in[21];
  const float* bq = (const float*)d_in[22];
  const float* Wk = (const float*)d_in[23];
  const float* bk = (const float*)d_in[24];
  const float* Wv = (const float*)d_in[25];
  const float* bv = (const float*)d_in[26];
  const float* Wo = (const float*)d_in[27];
  const float* bo = (const float*)d_in[28];
  const float* lnf_s = (const float*)d_in[29];
  const float* lnf_b = (const float*)d_in[30];
  float* out = (float*)d_out;

  char* w = (char*)d_ws;
  unsigned short* h16 = (unsigned short*)w;   w += (size_t)MPAD*D_*2;
  unsigned short* hn_bf = (unsigned short*)w; w += (size_t)MPAD*D_*2;
  unsigned short* A_bf = (unsigned short*)w;  w += (size_t)MPAD*512*2;
  unsigned short* Wt = (unsigned short*)w;    w += (size_t)3*256*512*2;
  float* scores = (float*)w;                  w += (size_t)B_*8*N_*4;
  float* rowstats = (float*)w;                w += (size_t)BN_*2*4;
  float* q_in = (float*)w;                    w += B_*D_*4;
  float* Wq_eff = (float*)w;                  w += B_*8*D_*4;
  float* qconst = (float*)w;                  w += B_*8*4;
  float* pm = (float*)w;                      w += 320*4;
  float* ps = (float*)w;                      w += 320*4;
  float* kbar = (float*)w;                    w += B_*8*D_*4;
  float* prep = (float*)w;                    w += 512*4;
  int* counts = (int*)w;                      w += BN_*4;
  int* cursor = (int*)w;                      w += BN_*4;
  int* offsets = (int*)w;                     w += (BN_+1)*4;
  int* bsum = (int*)w;                        w += SCAN_NBLK*4;
  int* boff = (int*)w;                        w += SCAN_NBLK*4;
  int* s_send = (int*)w;                      w += (size_t)B_*E_*4;
  float* ef_slot = (float*)w;                 w += (size_t)B_*E_*16*4;
  float* stats = (float*)w;                   w += (size_t)B_*E_*2*4;

  hipMemsetAsync(counts, 0, sizeof(int)*(size_t)2*BN_, stream);   // counts+cursor
  hipMemsetAsync(kbar, 0, sizeof(float)*(size_t)B_*8*D_, stream);

  k_node_in<<<BN_/16, 256, 0, stream>>>(nf, gf, W_node, b_node, ln_s, ln_b, hn_bf);
  k_hist<<<B_*E_/256, 256, 0, stream>>>(el, emask, counts);
  k_scanA<<<SCAN_NBLK, 256, 0, stream>>>(counts, bsum);
  k_scanB_eprep<<<2, 256, 0, stream>>>(bsum, boff, W_edge, b_edge, prep);
  k_scanC<<<SCAN_NBLK, 256, 0, stream>>>(counts, boff, offsets);
  k_fill<<<B_*E_/256, 256, 0, stream>>>(el, emask, ef, prep, offsets, cursor,
                                        s_send, ef_slot, stats);
  k_wt<<<384, 256, 0, stream>>>(gcn_W, Wt);
  k_se_wave<<<BN_/4, 256, 0, stream>>>(ef_slot, stats, W_edge, b_edge,
                                       ln_e_s, ln_e_b, offsets, A_bf);

  for(int i=0;i<3;i++){
    k_agg<<<BN_/4, 256, 0, stream>>>(hn_bf, offsets, s_send, A_bf);
    k_gemm_mfma<<<(MPAD/128)*2, 256, 0, stream>>>(A_bf, Wt + (size_t)i*256*512,
                                                  gcn_b + i*D_, counts, hn_bf, h16);
    if(i < 2)
      k_ln_relu<<<BN_/4, 256, 0, stream>>>(h16, ln_s + (i+1)*D_, ln_b + (i+1)*D_, hn_bf);
  }

  k_qprep<<<B_, 256, 0, stream>>>(h16, agent, lnq_s, lnq_b, Wq, bq, Wk, bk,
                                  q_in, Wq_eff, qconst);
  k_scores<<<BN_/4, 256, 0, stream>>>(h16, lnk_s, lnk_b, Wq_eff, qconst, nmask,
                                      rowstats, scores);
  k_softA<<<320, 256, 0, stream>>>(scores, pm, ps);
  k_kbar<<<B_*250, 256, 0, stream>>>(h16, rowstats, scores, pm, ps,
                                     lnk_s, lnk_b, kbar);
  k_final<<<B_, 256, 0, stream>>>(kbar, Wv, bv, Wo, bo, q_in, lnf_s, lnf_b, out);
}